// Round 8
// baseline (541.882 us; speedup 1.0000x reference)
//
#include <hip/hip_runtime.h>
#include <hip/hip_fp16.h>
#include <math.h>

#define NE 150000

// type ids: SB=0 PQ=1 PV=2 NB=3
__constant__ int c_stype[15] = {2,0,0,2,3,1,0,1,3,1,2,3,2,1,3};
__constant__ int c_dtype[15] = {0,1,3,1,1,3,2,0,0,2,3,2,2,1,3};
__constant__ int c_slot[15]  = {0,0,0,1,2,1,0,1,2,1,2,2,3,3,3};
__constant__ int c_N[4]      = {4000,30000,15000,12000};
__constant__ int c_xoff[4]   = {0,4000,34000,49000};
__constant__ int c_cnt[4]    = {3,4,4,4};
__constant__ int c_aggoff[4] = {0,24000,264000,384000};
__constant__ int c_outoff[4] = {0,48000,528000,768000};
__constant__ int c_aggrows[4]= {24000,240000,120000,96000};
// bucket id prefix: tiles per type = ceil(N[dtype]/1024)
__constant__ int c_tprefix[16] = {0,4,34,46,76,106,118,133,137,141,156,168,183,198,228,240};
// per-type row-meta offsets (stride N+1, slack unused)
__constant__ int c_toff2[15] = {0,4001,34002,46003,76004,106005,118006,133007,137008,141009,156010,168011,183012,198013,228014};

__device__ __forceinline__ float eluf(float x){ return x > 0.0f ? x : expm1f(x); }
__device__ __forceinline__ float elufast(float x){ return x > 0.0f ? x : __expf(x)-1.0f; }
__device__ __forceinline__ unsigned encf(float f){ unsigned u=__float_as_uint(f); return (u&0x80000000u)? ~u : (u|0x80000000u); }
__device__ __forceinline__ float decf(unsigned u){ return __uint_as_float((u&0x80000000u)? (u^0x80000000u) : ~u); }

// ---- build x = concat(x_nt, c_nt) for all 61000 nodes ----
__global__ __launch_bounds__(256) void k_build_x(
    const float* __restrict__ xSB, const float* __restrict__ cSB,
    const float* __restrict__ xPQ, const float* __restrict__ cPQ,
    const float* __restrict__ xPV, const float* __restrict__ cPV,
    const float* __restrict__ xNB, const float* __restrict__ cNB,
    float* __restrict__ xall){
  int n = blockIdx.x*256 + threadIdx.x;
  if (n >= 61000) return;
  const float *xp, *cp; int local;
  if (n < 4000)      { xp=xSB; cp=cSB; local=n; }
  else if (n < 34000){ xp=xPQ; cp=cPQ; local=n-4000; }
  else if (n < 49000){ xp=xPV; cp=cPV; local=n-34000; }
  else               { xp=xNB; cp=cNB; local=n-49000; }
  float4 a = ((const float4*)xp)[local];
  float4 b = ((const float4*)cp)[local];
  ((float4*)xall)[n*2+0] = a;
  ((float4*)xall)[n*2+1] = b;
}

__device__ __forceinline__ float dot128(const float* __restrict__ a, const float* __restrict__ b){
  const float4* a4 = (const float4*)a; const float4* b4 = (const float4*)b;
  float s = 0.f;
  #pragma unroll
  for (int h=0; h<32; h++){
    float4 A=a4[h], B=b4[h];
    s = fmaf(A.x,B.x,s); s = fmaf(A.y,B.y,s); s = fmaf(A.z,B.z,s); s = fmaf(A.w,B.w,s);
  }
  return s;
}
__device__ __forceinline__ void halfsum(const float* __restrict__ a, float& s0, float& s1){
  const float4* a4 = (const float4*)a;
  float x0=0.f, x1=0.f;
  #pragma unroll
  for (int h=0; h<16; h++){ float4 A=a4[h]; x0 += A.x+A.y+A.z+A.w; }
  #pragma unroll
  for (int h=16; h<32; h++){ float4 A=a4[h]; x1 += A.x+A.y+A.z+A.w; }
  s0=x0; s1=x1;
}

// ---- derive per-conv small params (160 floats per conv) ----
__global__ __launch_bounds__(128) void k_params(
    const float* __restrict__ Wq, const float* __restrict__ bq,
    const float* __restrict__ Wk, const float* __restrict__ bk,
    const float* __restrict__ Wv, const float* __restrict__ bv,
    const float* __restrict__ We, const float* __restrict__ be,
    const float* __restrict__ Ws, const float* __restrict__ bs,
    float* __restrict__ par){
  const int c = blockIdx.x, tid = threadIdx.x;
  const float* wq = Wq + (size_t)c*1024;
  const float* wk = Wk + (size_t)c*1024;
  const float* wv = Wv + (size_t)c*1024;
  const float* ws = Ws + (size_t)c*1024;
  const float* we = We + (size_t)c*256;
  const float* vbq = bq + (size_t)c*128;
  const float* vbk = bk + (size_t)c*128;
  const float* vbv = bv + (size_t)c*128;
  const float* vbe = be + (size_t)c*128;
  const float* vbs = bs + (size_t)c*128;
  float* P = par + (size_t)c*160;
  if (tid < 64){
    int fd = tid>>3, fs = tid&7;
    P[tid] = dot128(wq + fd*128, wk + fs*128);
    return;
  }
  const int job = tid - 64, grp = job>>3, f = job&7;
  if (grp==0) P[64+f] = dot128(wq + f*128, vbk);
  else if (grp==1) P[72+f] = dot128(wk + f*128, vbq);
  else if (grp==2) P[80+f] = dot128(wq + f*128, we);
  else if (grp==3) P[88+f] = dot128(wq + f*128, we+128);
  else if (grp==4) P[96+f] = dot128(wq + f*128, vbe);
  else if (grp==5){ float s0,s1; halfsum(wv + f*128, s0,s1); P[104+f]=s0; P[112+f]=s1; }
  else if (grp==6){ float s0,s1; halfsum(ws + f*128, s0,s1); P[120+f]=s0; P[128+f]=s1; }
  else {
    if (f==0){ P[136] = dot128(vbq, vbk);
               float a,b; halfsum(vbs, a,b); P[148]=a; P[149]=b; }
    else if (f==1) P[137] = dot128(vbq, we);
    else if (f==2) P[138] = dot128(vbq, we+128);
    else if (f==3) P[139] = dot128(vbq, vbe);
    else if (f==4){ float a=0.f,b=0.f; for(int h=0;h<64;h++){a+=we[h]; b+=we[64+h];} P[140]=a; P[141]=b; }
    else if (f==5){ float a=0.f,b=0.f; for(int h=0;h<64;h++){a+=we[128+h]; b+=we[192+h];} P[142]=a; P[143]=b; }
    else if (f==6){ float a,b; halfsum(vbv, a,b); P[144]=a; P[145]=b; }
    else          { float a,b; halfsum(vbe, a,b); P[146]=a; P[147]=b; }
  }
}

// ---- transpose W_fc -> WT[nt][o][h] so k_final's h-runs are contiguous ----
__global__ __launch_bounds__(256) void k_prep(const float* __restrict__ Wfc,
                                              float* __restrict__ WT){
  const int nt = blockIdx.x;
  for (int k=threadIdx.x; k<4096; k+=256){
    const int o = k>>6, h = k&63;
    WT[nt*4096 + k] = Wfc[nt*4096 + h*64 + o];
  }
}

#define CHUNK 18750

// ---- stage 1a: per-type histogram of dst>>10 (each edge read once) ----
__global__ __launch_bounds__(1024) void k_count(const int* __restrict__ eidx,
                                                int* __restrict__ gcnt){
  const int t = blockIdx.y;
  __shared__ int cnt[32];
  if (threadIdx.x < 32) cnt[threadIdx.x] = 0;
  __syncthreads();
  const int* __restrict__ dstp = eidx + (size_t)(t*2+1)*NE;
  const int e0 = blockIdx.x*CHUNK, e1 = min(NE, e0+CHUNK);
  for (int e=e0+threadIdx.x; e<e1; e+=1024) atomicAdd(&cnt[dstp[e]>>10], 1);
  __syncthreads();
  if (threadIdx.x < 32 && cnt[threadIdx.x] > 0)
    atomicAdd(&gcnt[c_tprefix[t] + threadIdx.x], cnt[threadIdx.x]);
}

// ---- stage 1b: per-type exclusive scan of bucket counts ----
__global__ void k_scan(const int* __restrict__ gcnt, int* __restrict__ gofs,
                       int* __restrict__ gcur){
  const int t = threadIdx.x;
  if (t >= 15) return;
  const int b0 = c_tprefix[t], b1 = c_tprefix[t+1];
  int run = t*NE;
  for (int b=b0; b<b1; b++){ gofs[b]=run; gcur[b]=run; run += gcnt[b]; }
}

// ---- stage 1c: scatter packed (eid<<10)|dl into tile buckets ----
__global__ __launch_bounds__(1024) void k_scatter(const int* __restrict__ eidx,
    int* __restrict__ gcur, unsigned* __restrict__ ebuf){
  const int t = blockIdx.y;
  __shared__ int lcnt[32], lbase[32];
  if (threadIdx.x < 32) lcnt[threadIdx.x] = 0;
  __syncthreads();
  const int* __restrict__ dstp = eidx + (size_t)(t*2+1)*NE;
  const int e0 = blockIdx.x*CHUNK, e1 = min(NE, e0+CHUNK);
  for (int e=e0+threadIdx.x; e<e1; e+=1024) atomicAdd(&lcnt[dstp[e]>>10], 1);
  __syncthreads();
  if (threadIdx.x < 32){
    int cchk = lcnt[threadIdx.x];
    lbase[threadIdx.x] = cchk > 0 ? atomicAdd(&gcur[c_tprefix[t]+threadIdx.x], cchk) : 0;
  }
  __syncthreads();
  if (threadIdx.x < 32) lcnt[threadIdx.x] = 0;
  __syncthreads();
  for (int e=e0+threadIdx.x; e<e1; e+=1024){
    const int d = dstp[e];
    const int tile = d>>10, dl = d&1023;
    const int pos = lbase[tile] + atomicAdd(&lcnt[tile], 1);
    ebuf[pos] = ((unsigned)e<<10) | (unsigned)dl;
  }
}

// ---- stage 2: per-tile row sort. One block per tile bucket; reads ONLY its
// own bucket (sequential). Pass 1: row histogram + scan -> gs2/glen.
// Pass 2: scatter {src, f16x2 ea} into row-sorted erec. ----
__global__ __launch_bounds__(1024) void k_tsort(
    const unsigned* __restrict__ ebuf, const int* __restrict__ eidx,
    const float* __restrict__ eattr,
    const int* __restrict__ gofs, const int* __restrict__ gcnt,
    uint2* __restrict__ erec, int* __restrict__ gs2, int* __restrict__ glen){
  const int b = blockIdx.x;
  int t = 0;
  while (b >= c_tprefix[t+1]) ++t;
  const int tile = b - c_tprefix[t];
  const int dt = c_dtype[t];
  const int N = c_N[dt];
  const int nbase = tile << 10;
  const int tileN = min(1024, N - nbase);
  const int tid = threadIdx.x;
  const int lane = tid & 63, wid = tid >> 6;

  __shared__ int cnt[1024];
  __shared__ int wsum[16];

  cnt[tid] = 0;
  __syncthreads();
  const int start = gofs[b], count = gcnt[b];
  for (int k=tid; k<count; k+=1024) atomicAdd(&cnt[ebuf[start+k] & 1023u], 1);
  __syncthreads();
  const int v = cnt[tid];
  int inc = v;
  #pragma unroll
  for (int off=1; off<64; off<<=1){ int u = __shfl_up(inc, off); if (lane>=off) inc += u; }
  if (lane==63) wsum[wid] = inc;
  __syncthreads();
  if (tid==0){ int r=0; for (int k=0;k<16;k++){ int x=wsum[k]; wsum[k]=r; r+=x; } }
  __syncthreads();
  const int pref = wsum[wid] + inc - v;  // exclusive prefix within bucket
  if (tid < tileN){
    gs2 [c_toff2[t] + nbase + tid] = start + pref;
    glen[c_toff2[t] + nbase + tid] = v;
  }
  cnt[tid] = pref;
  __syncthreads();

  const int* __restrict__ srcp = eidx + (size_t)(t*2)*NE;
  const float2* __restrict__ ea2 = (const float2*)eattr + (size_t)t*NE;
  for (int k=tid; k<count; k+=1024){
    const unsigned u = ebuf[start+k];
    const int dl = u & 1023u;
    const int eid = u >> 10;
    const int pos = start + atomicAdd(&cnt[dl], 1);
    const float2 ea = ea2[eid];
    __half2 h2 = __floats2half2_rn(ea.x, ea.y);
    erec[pos] = make_uint2((unsigned)srcp[eid], *(unsigned*)&h2);
  }
}

// ---- gather: per (type,node) walk sorted run ONCE, both layers' convs in
// registers. Zero LDS/atomics in the loop. Fuses softmax, skip, minmax.
__global__ __launch_bounds__(256) void k_gather(
    const int* __restrict__ gs2, const int* __restrict__ glen,
    const uint2* __restrict__ erec,
    const float* __restrict__ xall, const float* __restrict__ par,
    const float* __restrict__ Wl, const float* __restrict__ bl,
    float* __restrict__ g, unsigned* __restrict__ mm){
  const int t = blockIdx.y;
  const int dt = c_dtype[t], st = c_stype[t];
  const int N = c_N[dt];
  if (blockIdx.x*256 >= N) return;
  __shared__ float sA[160], sB[160];
  __shared__ float wlb[192];
  __shared__ float smin[4], smax[4];
  const int tid = threadIdx.x;
  if (tid < 160){ sA[tid] = par[(size_t)t*160 + tid]; sB[tid] = par[(size_t)(15+t)*160 + tid]; }
  if (tid < 192) wlb[tid] = (tid<128)? Wl[tid] : bl[tid-128];
  __syncthreads();
  const int n = blockIdx.x*256 + tid;
  const bool valid = n < N;
  float lmin = 3.4e38f, lmax = -3.4e38f;
  if (valid){
    const float4* xdp = (const float4*)(xall + (size_t)(c_xoff[dt]+n)*8);
    float4 b0v = xdp[0], b1v = xdp[1];
    float xd[8] = {b0v.x,b0v.y,b0v.z,b0v.w,b1v.x,b1v.y,b1v.z,b1v.w};
    float r2a[8], r2b[8];
    #pragma unroll
    for (int fs=0; fs<8; fs++){
      float a = sA[72+fs], bb = sB[72+fs];
      #pragma unroll
      for (int fd=0; fd<8; fd++){ a = fmaf(xd[fd], sA[fd*8+fs], a); bb = fmaf(xd[fd], sB[fd*8+fs], bb); }
      r2a[fs]=a; r2b[fs]=bb;
    }
    float t0a=sA[137], t1a=sA[138], tba=sA[139], u0a=sA[136];
    float t0b=sB[137], t1b=sB[138], tbb=sB[139], u0b=sB[136];
    #pragma unroll
    for (int f=0;f<8;f++){
      t0a = fmaf(xd[f], sA[80+f], t0a);  t0b = fmaf(xd[f], sB[80+f], t0b);
      t1a = fmaf(xd[f], sA[88+f], t1a);  t1b = fmaf(xd[f], sB[88+f], t1b);
      tba = fmaf(xd[f], sA[96+f], tba);  tbb = fmaf(xd[f], sB[96+f], tbb);
      u0a = fmaf(xd[f], sA[64+f], u0a);  u0b = fmaf(xd[f], sB[64+f], u0b);
    }
    const float accda = u0a + tba, accdb = u0b + tbb;
    const int o = c_toff2[t];
    const int js = gs2[o+n], je = js + glen[o+n];
    float denA=0.f, n0A=0.f, n1A=0.f;
    float denB=0.f, n0B=0.f, n1B=0.f;
    for (int j=js; j<je; j++){
      const uint2 rec = erec[j];
      const int src = (int)rec.x;
      const __half2 h2 = *(const __half2*)&rec.y;
      const float eax = __low2float(h2), eay = __high2float(h2);
      const float4* xsp = (const float4*)(xall + (size_t)(c_xoff[st]+src)*8);
      float4 a0v = xsp[0], a1v = xsp[1];
      float xs[8] = {a0v.x,a0v.y,a0v.z,a0v.w,a1v.x,a1v.y,a1v.z,a1v.w};
      float accA = accda, accB = accdb;
      float v0A = fmaf(eax, sA[140], fmaf(eay, sA[142], sA[144]+sA[146]));
      float v1A = fmaf(eax, sA[141], fmaf(eay, sA[143], sA[145]+sA[147]));
      float v0B = fmaf(eax, sB[140], fmaf(eay, sB[142], sB[144]+sB[146]));
      float v1B = fmaf(eax, sB[141], fmaf(eay, sB[143], sB[145]+sB[147]));
      #pragma unroll
      for (int f=0;f<8;f++){
        accA = fmaf(xs[f], r2a[f], accA);   accB = fmaf(xs[f], r2b[f], accB);
        v0A  = fmaf(xs[f], sA[104+f], v0A); v0B  = fmaf(xs[f], sB[104+f], v0B);
        v1A  = fmaf(xs[f], sA[112+f], v1A); v1B  = fmaf(xs[f], sB[112+f], v1B);
      }
      accA = fmaf(eax, t0a, fmaf(eay, t1a, accA));
      accB = fmaf(eax, t0b, fmaf(eay, t1b, accB));
      const float peA = __expf(accA * 0.08838834764831845f);
      const float peB = __expf(accB * 0.08838834764831845f);
      denA += peA; n0A = fmaf(peA, v0A, n0A); n1A = fmaf(peA, v1A, n1A);
      denB += peB; n0B = fmaf(peB, v0B, n0B); n1B = fmaf(peB, v1B, n1B);
    }
    const float invA = 1.0f/(denA + 1e-16f);
    const float invB = 1.0f/(denB + 1e-16f);
    float s0a = fmaf(n0A, invA, sA[148]), s1a = fmaf(n1A, invA, sA[149]);
    float s0b = fmaf(n0B, invB, sB[148]), s1b = fmaf(n1B, invB, sB[149]);
    #pragma unroll
    for (int f=0;f<8;f++){
      s0a = fmaf(xd[f], sA[120+f], s0a); s1a = fmaf(xd[f], sA[128+f], s1a);
      s0b = fmaf(xd[f], sB[120+f], s0b); s1b = fmaf(xd[f], sB[128+f], s1b);
    }
    const int baseA = c_aggoff[dt] + (0*c_cnt[dt] + c_slot[t])*N + n;
    const int baseB = c_aggoff[dt] + (1*c_cnt[dt] + c_slot[t])*N + n;
    ((float2*)g)[baseA] = make_float2(s0a, s1a);
    ((float2*)g)[baseB] = make_float2(s0b, s1b);
    #pragma unroll
    for (int h=0;h<64;h++){
      float za = fmaf(s0a, wlb[h], fmaf(s1a, wlb[64+h], wlb[128+h]));
      float zb = fmaf(s0b, wlb[h], fmaf(s1b, wlb[64+h], wlb[128+h]));
      lmin = fminf(lmin, fminf(za,zb)); lmax = fmaxf(lmax, fmaxf(za,zb));
    }
  }
  #pragma unroll
  for (int m=32;m>=1;m>>=1){
    lmin = fminf(lmin, __shfl_xor(lmin,m));
    lmax = fmaxf(lmax, __shfl_xor(lmax,m));
  }
  const int wv = tid>>6;
  if ((tid&63)==0){ smin[wv]=lmin; smax[wv]=lmax; }
  __syncthreads();
  if (tid==0){
    float mn = fminf(fminf(smin[0],smin[1]), fminf(smin[2],smin[3]));
    float mx = fmaxf(fmaxf(smax[0],smax[1]), fmaxf(smax[2],smax[3]));
    atomicMin(&mm[0], encf(mn));
    atomicMax(&mm[1], encf(mx));
  }
}

// ---- final v3: lane=row, one wave = 64 rows. No readlane/shuffle/LDS.
// nrm[64] per-lane in VGPRs; weights are wave-uniform -> SGPR operands ->
// 1 v_fma per (h,o). Fast elu (v_exp) instead of libm expm1f. ----
__global__ __launch_bounds__(256) void k_final(
    const float* __restrict__ g, const unsigned* __restrict__ mm,
    const float* __restrict__ Wl, const float* __restrict__ bl,
    const float* __restrict__ WT, const float* __restrict__ bfc,
    const float* __restrict__ Wl2, const float* __restrict__ bl2,
    float* __restrict__ out){
  const int gw = blockIdx.x*4 + (threadIdx.x>>6);   // global wave id, 64 rows each
  const int lane = threadIdx.x & 63;
  int nt, wo;
  if (gw < 375)       { nt=0; wo=0; }
  else if (gw < 4125) { nt=1; wo=375; }
  else if (gw < 6000) { nt=2; wo=4125; }
  else                { nt=3; wo=6000; }
  const int R = c_aggrows[nt];
  const int r0 = (gw - wo)*64;   // row base within nt (all boundaries are x64)
  const float zmin = decf(mm[0]), zmax = decf(mm[1]);
  const float rmin = 0.1f*eluf(zmin);
  const float rmax = 0.9f + 0.1f*eluf(zmax);
  const float s2 = 2.0f/(rmax - rmin + 1e-5f);
  const float cc = fmaf(-rmin, s2, -1.0f);      // nrm = elu(z)*s2 + cc
  const float2 gv = ((const float2*)g)[c_aggoff[nt] + r0 + lane];
  const float g0 = gv.x, g1 = gv.y;
  float nrm[64];
  #pragma unroll
  for (int h=0; h<64; h++){
    const float z = fmaf(g0, Wl[h], fmaf(g1, Wl[64+h], bl[h]));
    nrm[h] = fmaf(elufast(z), s2, cc);
  }
  const float* __restrict__ wt = WT + nt*4096;
  const float* __restrict__ bf = bfc + nt*64;
  float h0 = 0.f, h1 = 0.f;
  #pragma unroll 4
  for (int o=0; o<64; o++){
    float acc = bf[o];
    #pragma unroll
    for (int h=0; h<64; h++) acc = fmaf(nrm[h], wt[o*64+h], acc);
    const float b = elufast(acc);
    if (o < 32) h0 += b; else h1 += b;
  }
  const size_t orow = (size_t)c_outoff[nt] + r0 + lane;
  float4* o1 = (float4*)(out + orow*64);
  float4* o2 = (float4*)(out + (orow + (size_t)R)*64);
  #pragma unroll 4
  for (int q=0; q<16; q++){
    float4 buf;
    buf.x = elufast(fmaf(h0, Wl2[q*4+0], fmaf(h1, Wl2[64+q*4+0], bl2[q*4+0])));
    buf.y = elufast(fmaf(h0, Wl2[q*4+1], fmaf(h1, Wl2[64+q*4+1], bl2[q*4+1])));
    buf.z = elufast(fmaf(h0, Wl2[q*4+2], fmaf(h1, Wl2[64+q*4+2], bl2[q*4+2])));
    buf.w = elufast(fmaf(h0, Wl2[q*4+3], fmaf(h1, Wl2[64+q*4+3], bl2[q*4+3])));
    o1[q] = buf;
    o2[q] = buf;
  }
}

extern "C" void kernel_launch(void* const* d_in, const int* in_sizes, int n_in,
                              void* d_out, int out_size, void* d_ws, size_t ws_size,
                              hipStream_t stream) {
  const float* xSB = (const float*)d_in[0];
  const float* cSB = (const float*)d_in[1];
  const float* xPQ = (const float*)d_in[2];
  const float* cPQ = (const float*)d_in[3];
  const float* xPV = (const float*)d_in[4];
  const float* cPV = (const float*)d_in[5];
  const float* xNB = (const float*)d_in[6];
  const float* cNB = (const float*)d_in[7];
  const int*   eidx = (const int*)d_in[8];
  const float* eattr= (const float*)d_in[9];
  const float* Wq = (const float*)d_in[10];
  const float* bq = (const float*)d_in[11];
  const float* Wk = (const float*)d_in[12];
  const float* bk = (const float*)d_in[13];
  const float* Wv = (const float*)d_in[14];
  const float* bv = (const float*)d_in[15];
  const float* We = (const float*)d_in[16];
  const float* be = (const float*)d_in[17];
  const float* Ws = (const float*)d_in[18];
  const float* bs = (const float*)d_in[19];
  const float* Wl = (const float*)d_in[20];
  const float* bl = (const float*)d_in[21];
  const float* Wfc= (const float*)d_in[22];
  const float* bfc= (const float*)d_in[23];
  const float* Wl2= (const float*)d_in[24];
  const float* bl2= (const float*)d_in[25];

  float* ws    = (float*)d_ws;
  float* xall  = ws + 0;                    // 488000 f
  float* par   = ws + 488000;               // 4800 f
  int* gs2     = (int*)(ws + 492800);       // 240015 i
  int* glen    = (int*)(ws + 732815);       // 240015 i
  int* gcnt    = (int*)(ws + 972830);       // 240 i
  int* gofs    = (int*)(ws + 973070);       // 240 i
  int* gcur    = (int*)(ws + 973310);       // 240 i
  unsigned* mm = (unsigned*)(ws + 973550);  // 2
  unsigned* ebuf = (unsigned*)(ws + 973552);// 2250000 u32 (stage-1 buckets)
  float* g     = ws + 973552;               // 960000 f (aliases ebuf; ebuf dead after k_tsort)
  uint2* erec  = (uint2*)(ws + 3223552);    // 2250000 uint2 (even offset -> 8B aligned)
  float* WT    = ws + 7723552;              // 16384 f (transposed fc weights)
  // end: 7739936 floats ~= 31.0 MB

  hipMemsetAsync(gcnt, 0, 240*sizeof(int), stream);
  hipMemsetAsync(mm,   0xFF, 4, stream);
  hipMemsetAsync(mm+1, 0x00, 4, stream);

  k_build_x<<<(61000+255)/256, 256, 0, stream>>>(xSB,cSB,xPQ,cPQ,xPV,cPV,xNB,cNB, xall);
  k_params<<<30, 128, 0, stream>>>(Wq,bq,Wk,bk,Wv,bv,We,be,Ws,bs, par);
  k_prep<<<4, 256, 0, stream>>>(Wfc, WT);
  dim3 gb(8, 15);
  k_count<<<gb, 1024, 0, stream>>>(eidx, gcnt);
  k_scan<<<1, 64, 0, stream>>>(gcnt, gofs, gcur);
  k_scatter<<<gb, 1024, 0, stream>>>(eidx, gcur, ebuf);
  k_tsort<<<240, 1024, 0, stream>>>(ebuf, eidx, eattr, gofs, gcnt, erec, gs2, glen);
  dim3 gg((30000+255)/256, 15);
  k_gather<<<gg, 256, 0, stream>>>(gs2, glen, erec, xall, par, Wl, bl, g, mm);
  k_final<<<1875, 256, 0, stream>>>(g, mm, Wl, bl, WT, bfc, Wl2, bl2, (float*)d_out);
}

// Round 9
// 491.054 us; speedup vs baseline: 1.1035x; 1.1035x over previous
//
#include <hip/hip_runtime.h>
#include <hip/hip_fp16.h>
#include <math.h>

#define NE 150000

// type ids: SB=0 PQ=1 PV=2 NB=3
__constant__ int c_stype[15] = {2,0,0,2,3,1,0,1,3,1,2,3,2,1,3};
__constant__ int c_dtype[15] = {0,1,3,1,1,3,2,0,0,2,3,2,2,1,3};
__constant__ int c_slot[15]  = {0,0,0,1,2,1,0,1,2,1,2,2,3,3,3};
__constant__ int c_N[4]      = {4000,30000,15000,12000};
__constant__ int c_xoff[4]   = {0,4000,34000,49000};
__constant__ int c_cnt[4]    = {3,4,4,4};
__constant__ int c_aggoff[4] = {0,24000,264000,384000};
__constant__ int c_outoff[4] = {0,48000,528000,768000};
__constant__ int c_aggrows[4]= {24000,240000,120000,96000};
// bucket id prefix: tiles per type = ceil(N[dtype]/1024)
__constant__ int c_tprefix[16] = {0,4,34,46,76,106,118,133,137,141,156,168,183,198,228,240};
// per-type row-meta offsets (stride N+1, slack unused)
__constant__ int c_toff2[15] = {0,4001,34002,46003,76004,106005,118006,133007,137008,141009,156010,168011,183012,198013,228014};

__device__ __forceinline__ float eluf(float x){ return x > 0.0f ? x : expm1f(x); }
__device__ __forceinline__ float elufast(float x){ return x > 0.0f ? x : __expf(x)-1.0f; }
__device__ __forceinline__ unsigned encf(float f){ unsigned u=__float_as_uint(f); return (u&0x80000000u)? ~u : (u|0x80000000u); }
__device__ __forceinline__ float decf(unsigned u){ return __uint_as_float((u&0x80000000u)? (u^0x80000000u) : ~u); }
__device__ __forceinline__ float RL(float v, int l){ return __uint_as_float(__builtin_amdgcn_readlane(__float_as_uint(v), l)); }

// ---- build x = concat(x_nt, c_nt) for all 61000 nodes ----
__global__ __launch_bounds__(256) void k_build_x(
    const float* __restrict__ xSB, const float* __restrict__ cSB,
    const float* __restrict__ xPQ, const float* __restrict__ cPQ,
    const float* __restrict__ xPV, const float* __restrict__ cPV,
    const float* __restrict__ xNB, const float* __restrict__ cNB,
    float* __restrict__ xall){
  int n = blockIdx.x*256 + threadIdx.x;
  if (n >= 61000) return;
  const float *xp, *cp; int local;
  if (n < 4000)      { xp=xSB; cp=cSB; local=n; }
  else if (n < 34000){ xp=xPQ; cp=cPQ; local=n-4000; }
  else if (n < 49000){ xp=xPV; cp=cPV; local=n-34000; }
  else               { xp=xNB; cp=cNB; local=n-49000; }
  float4 a = ((const float4*)xp)[local];
  float4 b = ((const float4*)cp)[local];
  ((float4*)xall)[n*2+0] = a;
  ((float4*)xall)[n*2+1] = b;
}

__device__ __forceinline__ float dot128(const float* __restrict__ a, const float* __restrict__ b){
  const float4* a4 = (const float4*)a; const float4* b4 = (const float4*)b;
  float s = 0.f;
  #pragma unroll
  for (int h=0; h<32; h++){
    float4 A=a4[h], B=b4[h];
    s = fmaf(A.x,B.x,s); s = fmaf(A.y,B.y,s); s = fmaf(A.z,B.z,s); s = fmaf(A.w,B.w,s);
  }
  return s;
}
__device__ __forceinline__ void halfsum(const float* __restrict__ a, float& s0, float& s1){
  const float4* a4 = (const float4*)a;
  float x0=0.f, x1=0.f;
  #pragma unroll
  for (int h=0; h<16; h++){ float4 A=a4[h]; x0 += A.x+A.y+A.z+A.w; }
  #pragma unroll
  for (int h=16; h<32; h++){ float4 A=a4[h]; x1 += A.x+A.y+A.z+A.w; }
  s0=x0; s1=x1;
}

// ---- derive per-conv small params (160 floats per conv) ----
__global__ __launch_bounds__(128) void k_params(
    const float* __restrict__ Wq, const float* __restrict__ bq,
    const float* __restrict__ Wk, const float* __restrict__ bk,
    const float* __restrict__ Wv, const float* __restrict__ bv,
    const float* __restrict__ We, const float* __restrict__ be,
    const float* __restrict__ Ws, const float* __restrict__ bs,
    float* __restrict__ par){
  const int c = blockIdx.x, tid = threadIdx.x;
  const float* wq = Wq + (size_t)c*1024;
  const float* wk = Wk + (size_t)c*1024;
  const float* wv = Wv + (size_t)c*1024;
  const float* ws = Ws + (size_t)c*1024;
  const float* we = We + (size_t)c*256;
  const float* vbq = bq + (size_t)c*128;
  const float* vbk = bk + (size_t)c*128;
  const float* vbv = bv + (size_t)c*128;
  const float* vbe = be + (size_t)c*128;
  const float* vbs = bs + (size_t)c*128;
  float* P = par + (size_t)c*160;
  if (tid < 64){
    int fd = tid>>3, fs = tid&7;
    P[tid] = dot128(wq + fd*128, wk + fs*128);
    return;
  }
  const int job = tid - 64, grp = job>>3, f = job&7;
  if (grp==0) P[64+f] = dot128(wq + f*128, vbk);
  else if (grp==1) P[72+f] = dot128(wk + f*128, vbq);
  else if (grp==2) P[80+f] = dot128(wq + f*128, we);
  else if (grp==3) P[88+f] = dot128(wq + f*128, we+128);
  else if (grp==4) P[96+f] = dot128(wq + f*128, vbe);
  else if (grp==5){ float s0,s1; halfsum(wv + f*128, s0,s1); P[104+f]=s0; P[112+f]=s1; }
  else if (grp==6){ float s0,s1; halfsum(ws + f*128, s0,s1); P[120+f]=s0; P[128+f]=s1; }
  else {
    if (f==0){ P[136] = dot128(vbq, vbk);
               float a,b; halfsum(vbs, a,b); P[148]=a; P[149]=b; }
    else if (f==1) P[137] = dot128(vbq, we);
    else if (f==2) P[138] = dot128(vbq, we+128);
    else if (f==3) P[139] = dot128(vbq, vbe);
    else if (f==4){ float a=0.f,b=0.f; for(int h=0;h<64;h++){a+=we[h]; b+=we[64+h];} P[140]=a; P[141]=b; }
    else if (f==5){ float a=0.f,b=0.f; for(int h=0;h<64;h++){a+=we[128+h]; b+=we[192+h];} P[142]=a; P[143]=b; }
    else if (f==6){ float a,b; halfsum(vbv, a,b); P[144]=a; P[145]=b; }
    else          { float a,b; halfsum(vbe, a,b); P[146]=a; P[147]=b; }
  }
}

// ---- transpose W_fc -> WT[nt][o][h] so k_final's h-runs are contiguous ----
__global__ __launch_bounds__(256) void k_prep(const float* __restrict__ Wfc,
                                              float* __restrict__ WT){
  const int nt = blockIdx.x;
  for (int k=threadIdx.x; k<4096; k+=256){
    const int o = k>>6, h = k&63;
    WT[nt*4096 + k] = Wfc[nt*4096 + h*64 + o];
  }
}

#define CHUNK 18750

// ---- stage 1a: per-type histogram of dst>>10 (each edge read once) ----
__global__ __launch_bounds__(1024) void k_count(const int* __restrict__ eidx,
                                                int* __restrict__ gcnt){
  const int t = blockIdx.y;
  __shared__ int cnt[32];
  if (threadIdx.x < 32) cnt[threadIdx.x] = 0;
  __syncthreads();
  const int* __restrict__ dstp = eidx + (size_t)(t*2+1)*NE;
  const int e0 = blockIdx.x*CHUNK, e1 = min(NE, e0+CHUNK);
  for (int e=e0+threadIdx.x; e<e1; e+=1024) atomicAdd(&cnt[dstp[e]>>10], 1);
  __syncthreads();
  if (threadIdx.x < 32 && cnt[threadIdx.x] > 0)
    atomicAdd(&gcnt[c_tprefix[t] + threadIdx.x], cnt[threadIdx.x]);
}

// ---- stage 1b: per-type exclusive scan of bucket counts ----
__global__ void k_scan(const int* __restrict__ gcnt, int* __restrict__ gofs,
                       int* __restrict__ gcur){
  const int t = threadIdx.x;
  if (t >= 15) return;
  const int b0 = c_tprefix[t], b1 = c_tprefix[t+1];
  int run = t*NE;
  for (int b=b0; b<b1; b++){ gofs[b]=run; gcur[b]=run; run += gcnt[b]; }
}

// ---- stage 1c: scatter packed (eid<<10)|dl into tile buckets ----
__global__ __launch_bounds__(1024) void k_scatter(const int* __restrict__ eidx,
    int* __restrict__ gcur, unsigned* __restrict__ ebuf){
  const int t = blockIdx.y;
  __shared__ int lcnt[32], lbase[32];
  if (threadIdx.x < 32) lcnt[threadIdx.x] = 0;
  __syncthreads();
  const int* __restrict__ dstp = eidx + (size_t)(t*2+1)*NE;
  const int e0 = blockIdx.x*CHUNK, e1 = min(NE, e0+CHUNK);
  for (int e=e0+threadIdx.x; e<e1; e+=1024) atomicAdd(&lcnt[dstp[e]>>10], 1);
  __syncthreads();
  if (threadIdx.x < 32){
    int cchk = lcnt[threadIdx.x];
    lbase[threadIdx.x] = cchk > 0 ? atomicAdd(&gcur[c_tprefix[t]+threadIdx.x], cchk) : 0;
  }
  __syncthreads();
  if (threadIdx.x < 32) lcnt[threadIdx.x] = 0;
  __syncthreads();
  for (int e=e0+threadIdx.x; e<e1; e+=1024){
    const int d = dstp[e];
    const int tile = d>>10, dl = d&1023;
    const int pos = lbase[tile] + atomicAdd(&lcnt[tile], 1);
    ebuf[pos] = ((unsigned)e<<10) | (unsigned)dl;
  }
}

// ---- stage 2: per-tile row sort. One block per tile bucket; reads ONLY its
// own bucket (sequential). Pass 1: row histogram + scan -> gs2/glen.
// Pass 2: scatter {src, f16x2 ea} into row-sorted erec. ----
__global__ __launch_bounds__(1024) void k_tsort(
    const unsigned* __restrict__ ebuf, const int* __restrict__ eidx,
    const float* __restrict__ eattr,
    const int* __restrict__ gofs, const int* __restrict__ gcnt,
    uint2* __restrict__ erec, int* __restrict__ gs2, int* __restrict__ glen){
  const int b = blockIdx.x;
  int t = 0;
  while (b >= c_tprefix[t+1]) ++t;
  const int tile = b - c_tprefix[t];
  const int dt = c_dtype[t];
  const int N = c_N[dt];
  const int nbase = tile << 10;
  const int tileN = min(1024, N - nbase);
  const int tid = threadIdx.x;
  const int lane = tid & 63, wid = tid >> 6;

  __shared__ int cnt[1024];
  __shared__ int wsum[16];

  cnt[tid] = 0;
  __syncthreads();
  const int start = gofs[b], count = gcnt[b];
  for (int k=tid; k<count; k+=1024) atomicAdd(&cnt[ebuf[start+k] & 1023u], 1);
  __syncthreads();
  const int v = cnt[tid];
  int inc = v;
  #pragma unroll
  for (int off=1; off<64; off<<=1){ int u = __shfl_up(inc, off); if (lane>=off) inc += u; }
  if (lane==63) wsum[wid] = inc;
  __syncthreads();
  if (tid==0){ int r=0; for (int k=0;k<16;k++){ int x=wsum[k]; wsum[k]=r; r+=x; } }
  __syncthreads();
  const int pref = wsum[wid] + inc - v;  // exclusive prefix within bucket
  if (tid < tileN){
    gs2 [c_toff2[t] + nbase + tid] = start + pref;
    glen[c_toff2[t] + nbase + tid] = v;
  }
  cnt[tid] = pref;
  __syncthreads();

  const int* __restrict__ srcp = eidx + (size_t)(t*2)*NE;
  const float2* __restrict__ ea2 = (const float2*)eattr + (size_t)t*NE;
  for (int k=tid; k<count; k+=1024){
    const unsigned u = ebuf[start+k];
    const int dl = u & 1023u;
    const int eid = u >> 10;
    const int pos = start + atomicAdd(&cnt[dl], 1);
    const float2 ea = ea2[eid];
    __half2 h2 = __floats2half2_rn(ea.x, ea.y);
    erec[pos] = make_uint2((unsigned)srcp[eid], *(unsigned*)&h2);
  }
}

// ---- gather: per (type,node) walk sorted run ONCE, both layers' convs in
// registers. Zero LDS/atomics in the loop. Fuses softmax, skip, minmax.
__global__ __launch_bounds__(256) void k_gather(
    const int* __restrict__ gs2, const int* __restrict__ glen,
    const uint2* __restrict__ erec,
    const float* __restrict__ xall, const float* __restrict__ par,
    const float* __restrict__ Wl, const float* __restrict__ bl,
    float* __restrict__ g, unsigned* __restrict__ mm){
  const int t = blockIdx.y;
  const int dt = c_dtype[t], st = c_stype[t];
  const int N = c_N[dt];
  if (blockIdx.x*256 >= N) return;
  __shared__ float sA[160], sB[160];
  __shared__ float wlb[192];
  __shared__ float smin[4], smax[4];
  const int tid = threadIdx.x;
  if (tid < 160){ sA[tid] = par[(size_t)t*160 + tid]; sB[tid] = par[(size_t)(15+t)*160 + tid]; }
  if (tid < 192) wlb[tid] = (tid<128)? Wl[tid] : bl[tid-128];
  __syncthreads();
  const int n = blockIdx.x*256 + tid;
  const bool valid = n < N;
  float lmin = 3.4e38f, lmax = -3.4e38f;
  if (valid){
    const float4* xdp = (const float4*)(xall + (size_t)(c_xoff[dt]+n)*8);
    float4 b0v = xdp[0], b1v = xdp[1];
    float xd[8] = {b0v.x,b0v.y,b0v.z,b0v.w,b1v.x,b1v.y,b1v.z,b1v.w};
    float r2a[8], r2b[8];
    #pragma unroll
    for (int fs=0; fs<8; fs++){
      float a = sA[72+fs], bb = sB[72+fs];
      #pragma unroll
      for (int fd=0; fd<8; fd++){ a = fmaf(xd[fd], sA[fd*8+fs], a); bb = fmaf(xd[fd], sB[fd*8+fs], bb); }
      r2a[fs]=a; r2b[fs]=bb;
    }
    float t0a=sA[137], t1a=sA[138], tba=sA[139], u0a=sA[136];
    float t0b=sB[137], t1b=sB[138], tbb=sB[139], u0b=sB[136];
    #pragma unroll
    for (int f=0;f<8;f++){
      t0a = fmaf(xd[f], sA[80+f], t0a);  t0b = fmaf(xd[f], sB[80+f], t0b);
      t1a = fmaf(xd[f], sA[88+f], t1a);  t1b = fmaf(xd[f], sB[88+f], t1b);
      tba = fmaf(xd[f], sA[96+f], tba);  tbb = fmaf(xd[f], sB[96+f], tbb);
      u0a = fmaf(xd[f], sA[64+f], u0a);  u0b = fmaf(xd[f], sB[64+f], u0b);
    }
    const float accda = u0a + tba, accdb = u0b + tbb;
    const int o = c_toff2[t];
    const int js = gs2[o+n], je = js + glen[o+n];
    float denA=0.f, n0A=0.f, n1A=0.f;
    float denB=0.f, n0B=0.f, n1B=0.f;
    for (int j=js; j<je; j++){
      const uint2 rec = erec[j];
      const int src = (int)rec.x;
      const __half2 h2 = *(const __half2*)&rec.y;
      const float eax = __low2float(h2), eay = __high2float(h2);
      const float4* xsp = (const float4*)(xall + (size_t)(c_xoff[st]+src)*8);
      float4 a0v = xsp[0], a1v = xsp[1];
      float xs[8] = {a0v.x,a0v.y,a0v.z,a0v.w,a1v.x,a1v.y,a1v.z,a1v.w};
      float accA = accda, accB = accdb;
      float v0A = fmaf(eax, sA[140], fmaf(eay, sA[142], sA[144]+sA[146]));
      float v1A = fmaf(eax, sA[141], fmaf(eay, sA[143], sA[145]+sA[147]));
      float v0B = fmaf(eax, sB[140], fmaf(eay, sB[142], sB[144]+sB[146]));
      float v1B = fmaf(eax, sB[141], fmaf(eay, sB[143], sB[145]+sB[147]));
      #pragma unroll
      for (int f=0;f<8;f++){
        accA = fmaf(xs[f], r2a[f], accA);   accB = fmaf(xs[f], r2b[f], accB);
        v0A  = fmaf(xs[f], sA[104+f], v0A); v0B  = fmaf(xs[f], sB[104+f], v0B);
        v1A  = fmaf(xs[f], sA[112+f], v1A); v1B  = fmaf(xs[f], sB[112+f], v1B);
      }
      accA = fmaf(eax, t0a, fmaf(eay, t1a, accA));
      accB = fmaf(eax, t0b, fmaf(eay, t1b, accB));
      const float peA = __expf(accA * 0.08838834764831845f);
      const float peB = __expf(accB * 0.08838834764831845f);
      denA += peA; n0A = fmaf(peA, v0A, n0A); n1A = fmaf(peA, v1A, n1A);
      denB += peB; n0B = fmaf(peB, v0B, n0B); n1B = fmaf(peB, v1B, n1B);
    }
    const float invA = 1.0f/(denA + 1e-16f);
    const float invB = 1.0f/(denB + 1e-16f);
    float s0a = fmaf(n0A, invA, sA[148]), s1a = fmaf(n1A, invA, sA[149]);
    float s0b = fmaf(n0B, invB, sB[148]), s1b = fmaf(n1B, invB, sB[149]);
    #pragma unroll
    for (int f=0;f<8;f++){
      s0a = fmaf(xd[f], sA[120+f], s0a); s1a = fmaf(xd[f], sA[128+f], s1a);
      s0b = fmaf(xd[f], sB[120+f], s0b); s1b = fmaf(xd[f], sB[128+f], s1b);
    }
    const int baseA = c_aggoff[dt] + (0*c_cnt[dt] + c_slot[t])*N + n;
    const int baseB = c_aggoff[dt] + (1*c_cnt[dt] + c_slot[t])*N + n;
    ((float2*)g)[baseA] = make_float2(s0a, s1a);
    ((float2*)g)[baseB] = make_float2(s0b, s1b);
    #pragma unroll
    for (int h=0;h<64;h++){
      float za = fmaf(s0a, wlb[h], fmaf(s1a, wlb[64+h], wlb[128+h]));
      float zb = fmaf(s0b, wlb[h], fmaf(s1b, wlb[64+h], wlb[128+h]));
      lmin = fminf(lmin, fminf(za,zb)); lmax = fmaxf(lmax, fmaxf(za,zb));
    }
  }
  #pragma unroll
  for (int m=32;m>=1;m>>=1){
    lmin = fminf(lmin, __shfl_xor(lmin,m));
    lmax = fmaxf(lmax, __shfl_xor(lmax,m));
  }
  const int wv = tid>>6;
  if ((tid&63)==0){ smin[wv]=lmin; smax[wv]=lmax; }
  __syncthreads();
  if (tid==0){
    float mn = fminf(fminf(smin[0],smin[1]), fminf(smin[2],smin[3]));
    float mx = fmaxf(fmaxf(smax[0],smax[1]), fmaxf(smax[2],smax[3]));
    atomicMin(&mm[0], encf(mn));
    atomicMax(&mm[1], encf(mx));
  }
}

// ---- final v4: phase 1 lane=row (nrm[64] in VGPRs, 1 v_fma per (h,o) with
// SGPR weights); phase 2 lane=channel via 2 readlanes/row -> 256B coalesced
// stores. launch_bounds(256,1) keeps nrm[64] in registers (no spill). ----
__global__ __launch_bounds__(256, 1) void k_final(
    const float* __restrict__ g, const unsigned* __restrict__ mm,
    const float* __restrict__ Wl, const float* __restrict__ bl,
    const float* __restrict__ WT, const float* __restrict__ bfc,
    const float* __restrict__ Wl2, const float* __restrict__ bl2,
    float* __restrict__ out){
  const int gw = blockIdx.x*4 + (threadIdx.x>>6);   // global wave id, 64 rows each
  const int lane = threadIdx.x & 63;
  int nt, wo;
  if (gw < 375)       { nt=0; wo=0; }
  else if (gw < 4125) { nt=1; wo=375; }
  else if (gw < 6000) { nt=2; wo=4125; }
  else                { nt=3; wo=6000; }
  const int R = c_aggrows[nt];
  const int r0 = (gw - wo)*64;   // row base within nt (all boundaries are x64)
  const float zmin = decf(mm[0]), zmax = decf(mm[1]);
  const float rmin = 0.1f*eluf(zmin);
  const float rmax = 0.9f + 0.1f*eluf(zmax);
  const float s2 = 2.0f/(rmax - rmin + 1e-5f);
  const float cc = fmaf(-rmin, s2, -1.0f);      // nrm = elu(z)*s2 + cc
  const float2 gv = ((const float2*)g)[c_aggoff[nt] + r0 + lane];
  const float g0 = gv.x, g1 = gv.y;
  float nrm[64];
  #pragma unroll
  for (int h=0; h<64; h++){
    const float z = fmaf(g0, Wl[h], fmaf(g1, Wl[64+h], bl[h]));
    nrm[h] = fmaf(elufast(z), s2, cc);
  }
  const float* __restrict__ wt = WT + nt*4096;
  const float* __restrict__ bf = bfc + nt*64;
  float h0 = 0.f, h1 = 0.f;
  #pragma unroll 4
  for (int o=0; o<64; o++){
    float acc = bf[o];
    #pragma unroll
    for (int h=0; h<64; h++) acc = fmaf(nrm[h], wt[o*64+h], acc);
    const float b = elufast(acc);
    if (o < 32) h0 += b; else h1 += b;
  }
  // phase 2: lane = channel; broadcast (h0,h1) of row r via readlane;
  // 256B-contiguous stores, two copies (layer duplicate).
  const float wl2a = Wl2[lane], wl2b = Wl2[64+lane], bl2v = bl2[lane];
  float* __restrict__ o1 = out + ((size_t)c_outoff[nt] + r0)*64 + lane;
  float* __restrict__ o2 = o1 + (size_t)R*64;
  #pragma unroll
  for (int r=0; r<64; r++){
    const float hr0 = RL(h0, r), hr1 = RL(h1, r);
    const float f = elufast(fmaf(hr0, wl2a, fmaf(hr1, wl2b, bl2v)));
    o1[(size_t)r*64] = f;
    o2[(size_t)r*64] = f;
  }
}

extern "C" void kernel_launch(void* const* d_in, const int* in_sizes, int n_in,
                              void* d_out, int out_size, void* d_ws, size_t ws_size,
                              hipStream_t stream) {
  const float* xSB = (const float*)d_in[0];
  const float* cSB = (const float*)d_in[1];
  const float* xPQ = (const float*)d_in[2];
  const float* cPQ = (const float*)d_in[3];
  const float* xPV = (const float*)d_in[4];
  const float* cPV = (const float*)d_in[5];
  const float* xNB = (const float*)d_in[6];
  const float* cNB = (const float*)d_in[7];
  const int*   eidx = (const int*)d_in[8];
  const float* eattr= (const float*)d_in[9];
  const float* Wq = (const float*)d_in[10];
  const float* bq = (const float*)d_in[11];
  const float* Wk = (const float*)d_in[12];
  const float* bk = (const float*)d_in[13];
  const float* Wv = (const float*)d_in[14];
  const float* bv = (const float*)d_in[15];
  const float* We = (const float*)d_in[16];
  const float* be = (const float*)d_in[17];
  const float* Ws = (const float*)d_in[18];
  const float* bs = (const float*)d_in[19];
  const float* Wl = (const float*)d_in[20];
  const float* bl = (const float*)d_in[21];
  const float* Wfc= (const float*)d_in[22];
  const float* bfc= (const float*)d_in[23];
  const float* Wl2= (const float*)d_in[24];
  const float* bl2= (const float*)d_in[25];

  float* ws    = (float*)d_ws;
  float* xall  = ws + 0;                    // 488000 f
  float* par   = ws + 488000;               // 4800 f
  int* gs2     = (int*)(ws + 492800);       // 240015 i
  int* glen    = (int*)(ws + 732815);       // 240015 i
  int* gcnt    = (int*)(ws + 972830);       // 240 i
  int* gofs    = (int*)(ws + 973070);       // 240 i
  int* gcur    = (int*)(ws + 973310);       // 240 i
  unsigned* mm = (unsigned*)(ws + 973550);  // 2
  unsigned* ebuf = (unsigned*)(ws + 973552);// 2250000 u32 (stage-1 buckets)
  float* g     = ws + 973552;               // 960000 f (aliases ebuf; ebuf dead after k_tsort)
  uint2* erec  = (uint2*)(ws + 3223552);    // 2250000 uint2 (even offset -> 8B aligned)
  float* WT    = ws + 7723552;              // 16384 f (transposed fc weights)
  // end: 7739936 floats ~= 31.0 MB

  hipMemsetAsync(gcnt, 0, 240*sizeof(int), stream);
  hipMemsetAsync(mm,   0xFF, 4, stream);
  hipMemsetAsync(mm+1, 0x00, 4, stream);

  k_build_x<<<(61000+255)/256, 256, 0, stream>>>(xSB,cSB,xPQ,cPQ,xPV,cPV,xNB,cNB, xall);
  k_params<<<30, 128, 0, stream>>>(Wq,bq,Wk,bk,Wv,bv,We,be,Ws,bs, par);
  k_prep<<<4, 256, 0, stream>>>(Wfc, WT);
  dim3 gb(8, 15);
  k_count<<<gb, 1024, 0, stream>>>(eidx, gcnt);
  k_scan<<<1, 64, 0, stream>>>(gcnt, gofs, gcur);
  k_scatter<<<gb, 1024, 0, stream>>>(eidx, gcur, ebuf);
  k_tsort<<<240, 1024, 0, stream>>>(ebuf, eidx, eattr, gofs, gcnt, erec, gs2, glen);
  dim3 gg((30000+255)/256, 15);
  k_gather<<<gg, 256, 0, stream>>>(gs2, glen, erec, xall, par, Wl, bl, g, mm);
  k_final<<<1875, 256, 0, stream>>>(g, mm, Wl, bl, WT, bfc, Wl2, bl2, (float*)d_out);
}

// Round 10
// 351.603 us; speedup vs baseline: 1.5412x; 1.3966x over previous
//
#include <hip/hip_runtime.h>
#include <hip/hip_fp16.h>
#include <math.h>

#define NE 150000

// type ids: SB=0 PQ=1 PV=2 NB=3
__constant__ int c_stype[15] = {2,0,0,2,3,1,0,1,3,1,2,3,2,1,3};
__constant__ int c_dtype[15] = {0,1,3,1,1,3,2,0,0,2,3,2,2,1,3};
__constant__ int c_slot[15]  = {0,0,0,1,2,1,0,1,2,1,2,2,3,3,3};
__constant__ int c_N[4]      = {4000,30000,15000,12000};
__constant__ int c_xoff[4]   = {0,4000,34000,49000};
__constant__ int c_cnt[4]    = {3,4,4,4};
__constant__ int c_aggoff[4] = {0,24000,264000,384000};
__constant__ int c_outoff[4] = {0,48000,528000,768000};
__constant__ int c_aggrows[4]= {24000,240000,120000,96000};
// bucket id prefix: tiles per type = ceil(N[dtype]/1024)
__constant__ int c_tprefix[16] = {0,4,34,46,76,106,118,133,137,141,156,168,183,198,228,240};
// per-type row-meta offsets (stride N+1, slack unused)
__constant__ int c_toff2[15] = {0,4001,34002,46003,76004,106005,118006,133007,137008,141009,156010,168011,183012,198013,228014};

__device__ __forceinline__ float eluf(float x){ return x > 0.0f ? x : expm1f(x); }
__device__ __forceinline__ float elufast(float x){ return x > 0.0f ? x : __expf(x)-1.0f; }
__device__ __forceinline__ unsigned encf(float f){ unsigned u=__float_as_uint(f); return (u&0x80000000u)? ~u : (u|0x80000000u); }
__device__ __forceinline__ float decf(unsigned u){ return __uint_as_float((u&0x80000000u)? (u^0x80000000u) : ~u); }
__device__ __forceinline__ float RL(float v, int l){ return __uint_as_float(__builtin_amdgcn_readlane(__float_as_uint(v), l)); }

// ---- build x = concat(x_nt, c_nt) for all 61000 nodes ----
__global__ __launch_bounds__(256) void k_build_x(
    const float* __restrict__ xSB, const float* __restrict__ cSB,
    const float* __restrict__ xPQ, const float* __restrict__ cPQ,
    const float* __restrict__ xPV, const float* __restrict__ cPV,
    const float* __restrict__ xNB, const float* __restrict__ cNB,
    float* __restrict__ xall){
  int n = blockIdx.x*256 + threadIdx.x;
  if (n >= 61000) return;
  const float *xp, *cp; int local;
  if (n < 4000)      { xp=xSB; cp=cSB; local=n; }
  else if (n < 34000){ xp=xPQ; cp=cPQ; local=n-4000; }
  else if (n < 49000){ xp=xPV; cp=cPV; local=n-34000; }
  else               { xp=xNB; cp=cNB; local=n-49000; }
  float4 a = ((const float4*)xp)[local];
  float4 b = ((const float4*)cp)[local];
  ((float4*)xall)[n*2+0] = a;
  ((float4*)xall)[n*2+1] = b;
}

__device__ __forceinline__ float dot128(const float* __restrict__ a, const float* __restrict__ b){
  const float4* a4 = (const float4*)a; const float4* b4 = (const float4*)b;
  float s = 0.f;
  #pragma unroll
  for (int h=0; h<32; h++){
    float4 A=a4[h], B=b4[h];
    s = fmaf(A.x,B.x,s); s = fmaf(A.y,B.y,s); s = fmaf(A.z,B.z,s); s = fmaf(A.w,B.w,s);
  }
  return s;
}
__device__ __forceinline__ void halfsum(const float* __restrict__ a, float& s0, float& s1){
  const float4* a4 = (const float4*)a;
  float x0=0.f, x1=0.f;
  #pragma unroll
  for (int h=0; h<16; h++){ float4 A=a4[h]; x0 += A.x+A.y+A.z+A.w; }
  #pragma unroll
  for (int h=16; h<32; h++){ float4 A=a4[h]; x1 += A.x+A.y+A.z+A.w; }
  s0=x0; s1=x1;
}

// ---- derive per-conv small params (160 floats per conv) ----
__global__ __launch_bounds__(128) void k_params(
    const float* __restrict__ Wq, const float* __restrict__ bq,
    const float* __restrict__ Wk, const float* __restrict__ bk,
    const float* __restrict__ Wv, const float* __restrict__ bv,
    const float* __restrict__ We, const float* __restrict__ be,
    const float* __restrict__ Ws, const float* __restrict__ bs,
    float* __restrict__ par){
  const int c = blockIdx.x, tid = threadIdx.x;
  const float* wq = Wq + (size_t)c*1024;
  const float* wk = Wk + (size_t)c*1024;
  const float* wv = Wv + (size_t)c*1024;
  const float* ws = Ws + (size_t)c*1024;
  const float* we = We + (size_t)c*256;
  const float* vbq = bq + (size_t)c*128;
  const float* vbk = bk + (size_t)c*128;
  const float* vbv = bv + (size_t)c*128;
  const float* vbe = be + (size_t)c*128;
  const float* vbs = bs + (size_t)c*128;
  float* P = par + (size_t)c*160;
  if (tid < 64){
    int fd = tid>>3, fs = tid&7;
    P[tid] = dot128(wq + fd*128, wk + fs*128);
    return;
  }
  const int job = tid - 64, grp = job>>3, f = job&7;
  if (grp==0) P[64+f] = dot128(wq + f*128, vbk);
  else if (grp==1) P[72+f] = dot128(wk + f*128, vbq);
  else if (grp==2) P[80+f] = dot128(wq + f*128, we);
  else if (grp==3) P[88+f] = dot128(wq + f*128, we+128);
  else if (grp==4) P[96+f] = dot128(wq + f*128, vbe);
  else if (grp==5){ float s0,s1; halfsum(wv + f*128, s0,s1); P[104+f]=s0; P[112+f]=s1; }
  else if (grp==6){ float s0,s1; halfsum(ws + f*128, s0,s1); P[120+f]=s0; P[128+f]=s1; }
  else {
    if (f==0){ P[136] = dot128(vbq, vbk);
               float a,b; halfsum(vbs, a,b); P[148]=a; P[149]=b; }
    else if (f==1) P[137] = dot128(vbq, we);
    else if (f==2) P[138] = dot128(vbq, we+128);
    else if (f==3) P[139] = dot128(vbq, vbe);
    else if (f==4){ float a=0.f,b=0.f; for(int h=0;h<64;h++){a+=we[h]; b+=we[64+h];} P[140]=a; P[141]=b; }
    else if (f==5){ float a=0.f,b=0.f; for(int h=0;h<64;h++){a+=we[128+h]; b+=we[192+h];} P[142]=a; P[143]=b; }
    else if (f==6){ float a,b; halfsum(vbv, a,b); P[144]=a; P[145]=b; }
    else          { float a,b; halfsum(vbe, a,b); P[146]=a; P[147]=b; }
  }
}

#define CHUNK 18750

// ---- stage 1a: per-type histogram of dst>>10 (each edge read once) ----
__global__ __launch_bounds__(1024) void k_count(const int* __restrict__ eidx,
                                                int* __restrict__ gcnt){
  const int t = blockIdx.y;
  __shared__ int cnt[32];
  if (threadIdx.x < 32) cnt[threadIdx.x] = 0;
  __syncthreads();
  const int* __restrict__ dstp = eidx + (size_t)(t*2+1)*NE;
  const int e0 = blockIdx.x*CHUNK, e1 = min(NE, e0+CHUNK);
  for (int e=e0+threadIdx.x; e<e1; e+=1024) atomicAdd(&cnt[dstp[e]>>10], 1);
  __syncthreads();
  if (threadIdx.x < 32 && cnt[threadIdx.x] > 0)
    atomicAdd(&gcnt[c_tprefix[t] + threadIdx.x], cnt[threadIdx.x]);
}

// ---- stage 1b: per-type exclusive scan of bucket counts ----
__global__ void k_scan(const int* __restrict__ gcnt, int* __restrict__ gofs,
                       int* __restrict__ gcur){
  const int t = threadIdx.x;
  if (t >= 15) return;
  const int b0 = c_tprefix[t], b1 = c_tprefix[t+1];
  int run = t*NE;
  for (int b=b0; b<b1; b++){ gofs[b]=run; gcur[b]=run; run += gcnt[b]; }
}

// ---- stage 1c: scatter packed (eid<<10)|dl into tile buckets ----
__global__ __launch_bounds__(1024) void k_scatter(const int* __restrict__ eidx,
    int* __restrict__ gcur, unsigned* __restrict__ ebuf){
  const int t = blockIdx.y;
  __shared__ int lcnt[32], lbase[32];
  if (threadIdx.x < 32) lcnt[threadIdx.x] = 0;
  __syncthreads();
  const int* __restrict__ dstp = eidx + (size_t)(t*2+1)*NE;
  const int e0 = blockIdx.x*CHUNK, e1 = min(NE, e0+CHUNK);
  for (int e=e0+threadIdx.x; e<e1; e+=1024) atomicAdd(&lcnt[dstp[e]>>10], 1);
  __syncthreads();
  if (threadIdx.x < 32){
    int cchk = lcnt[threadIdx.x];
    lbase[threadIdx.x] = cchk > 0 ? atomicAdd(&gcur[c_tprefix[t]+threadIdx.x], cchk) : 0;
  }
  __syncthreads();
  if (threadIdx.x < 32) lcnt[threadIdx.x] = 0;
  __syncthreads();
  for (int e=e0+threadIdx.x; e<e1; e+=1024){
    const int d = dstp[e];
    const int tile = d>>10, dl = d&1023;
    const int pos = lbase[tile] + atomicAdd(&lcnt[tile], 1);
    ebuf[pos] = ((unsigned)e<<10) | (unsigned)dl;
  }
}

// ---- stage 2: per-tile row sort. One block per tile bucket; reads ONLY its
// own bucket (sequential). Pass 1: row histogram + scan -> gs2/glen.
// Pass 2: scatter {src, f16x2 ea} into row-sorted erec. ----
__global__ __launch_bounds__(1024) void k_tsort(
    const unsigned* __restrict__ ebuf, const int* __restrict__ eidx,
    const float* __restrict__ eattr,
    const int* __restrict__ gofs, const int* __restrict__ gcnt,
    uint2* __restrict__ erec, int* __restrict__ gs2, int* __restrict__ glen){
  const int b = blockIdx.x;
  int t = 0;
  while (b >= c_tprefix[t+1]) ++t;
  const int tile = b - c_tprefix[t];
  const int dt = c_dtype[t];
  const int N = c_N[dt];
  const int nbase = tile << 10;
  const int tileN = min(1024, N - nbase);
  const int tid = threadIdx.x;
  const int lane = tid & 63, wid = tid >> 6;

  __shared__ int cnt[1024];
  __shared__ int wsum[16];

  cnt[tid] = 0;
  __syncthreads();
  const int start = gofs[b], count = gcnt[b];
  for (int k=tid; k<count; k+=1024) atomicAdd(&cnt[ebuf[start+k] & 1023u], 1);
  __syncthreads();
  const int v = cnt[tid];
  int inc = v;
  #pragma unroll
  for (int off=1; off<64; off<<=1){ int u = __shfl_up(inc, off); if (lane>=off) inc += u; }
  if (lane==63) wsum[wid] = inc;
  __syncthreads();
  if (tid==0){ int r=0; for (int k=0;k<16;k++){ int x=wsum[k]; wsum[k]=r; r+=x; } }
  __syncthreads();
  const int pref = wsum[wid] + inc - v;  // exclusive prefix within bucket
  if (tid < tileN){
    gs2 [c_toff2[t] + nbase + tid] = start + pref;
    glen[c_toff2[t] + nbase + tid] = v;
  }
  cnt[tid] = pref;
  __syncthreads();

  const int* __restrict__ srcp = eidx + (size_t)(t*2)*NE;
  const float2* __restrict__ ea2 = (const float2*)eattr + (size_t)t*NE;
  for (int k=tid; k<count; k+=1024){
    const unsigned u = ebuf[start+k];
    const int dl = u & 1023u;
    const int eid = u >> 10;
    const int pos = start + atomicAdd(&cnt[dl], 1);
    const float2 ea = ea2[eid];
    __half2 h2 = __floats2half2_rn(ea.x, ea.y);
    erec[pos] = make_uint2((unsigned)srcp[eid], *(unsigned*)&h2);
  }
}

// ---- gather: per (type,node) walk sorted run ONCE, both layers' convs in
// registers. Zero LDS/atomics in the loop. Fuses softmax, skip, minmax.
__global__ __launch_bounds__(256) void k_gather(
    const int* __restrict__ gs2, const int* __restrict__ glen,
    const uint2* __restrict__ erec,
    const float* __restrict__ xall, const float* __restrict__ par,
    const float* __restrict__ Wl, const float* __restrict__ bl,
    float* __restrict__ g, unsigned* __restrict__ mm){
  const int t = blockIdx.y;
  const int dt = c_dtype[t], st = c_stype[t];
  const int N = c_N[dt];
  if (blockIdx.x*256 >= N) return;
  __shared__ float sA[160], sB[160];
  __shared__ float wlb[192];
  __shared__ float smin[4], smax[4];
  const int tid = threadIdx.x;
  if (tid < 160){ sA[tid] = par[(size_t)t*160 + tid]; sB[tid] = par[(size_t)(15+t)*160 + tid]; }
  if (tid < 192) wlb[tid] = (tid<128)? Wl[tid] : bl[tid-128];
  __syncthreads();
  const int n = blockIdx.x*256 + tid;
  const bool valid = n < N;
  float lmin = 3.4e38f, lmax = -3.4e38f;
  if (valid){
    const float4* xdp = (const float4*)(xall + (size_t)(c_xoff[dt]+n)*8);
    float4 b0v = xdp[0], b1v = xdp[1];
    float xd[8] = {b0v.x,b0v.y,b0v.z,b0v.w,b1v.x,b1v.y,b1v.z,b1v.w};
    float r2a[8], r2b[8];
    #pragma unroll
    for (int fs=0; fs<8; fs++){
      float a = sA[72+fs], bb = sB[72+fs];
      #pragma unroll
      for (int fd=0; fd<8; fd++){ a = fmaf(xd[fd], sA[fd*8+fs], a); bb = fmaf(xd[fd], sB[fd*8+fs], bb); }
      r2a[fs]=a; r2b[fs]=bb;
    }
    float t0a=sA[137], t1a=sA[138], tba=sA[139], u0a=sA[136];
    float t0b=sB[137], t1b=sB[138], tbb=sB[139], u0b=sB[136];
    #pragma unroll
    for (int f=0;f<8;f++){
      t0a = fmaf(xd[f], sA[80+f], t0a);  t0b = fmaf(xd[f], sB[80+f], t0b);
      t1a = fmaf(xd[f], sA[88+f], t1a);  t1b = fmaf(xd[f], sB[88+f], t1b);
      tba = fmaf(xd[f], sA[96+f], tba);  tbb = fmaf(xd[f], sB[96+f], tbb);
      u0a = fmaf(xd[f], sA[64+f], u0a);  u0b = fmaf(xd[f], sB[64+f], u0b);
    }
    const float accda = u0a + tba, accdb = u0b + tbb;
    const int o = c_toff2[t];
    const int js = gs2[o+n], je = js + glen[o+n];
    float denA=0.f, n0A=0.f, n1A=0.f;
    float denB=0.f, n0B=0.f, n1B=0.f;
    for (int j=js; j<je; j++){
      const uint2 rec = erec[j];
      const int src = (int)rec.x;
      const __half2 h2 = *(const __half2*)&rec.y;
      const float eax = __low2float(h2), eay = __high2float(h2);
      const float4* xsp = (const float4*)(xall + (size_t)(c_xoff[st]+src)*8);
      float4 a0v = xsp[0], a1v = xsp[1];
      float xs[8] = {a0v.x,a0v.y,a0v.z,a0v.w,a1v.x,a1v.y,a1v.z,a1v.w};
      float accA = accda, accB = accdb;
      float v0A = fmaf(eax, sA[140], fmaf(eay, sA[142], sA[144]+sA[146]));
      float v1A = fmaf(eax, sA[141], fmaf(eay, sA[143], sA[145]+sA[147]));
      float v0B = fmaf(eax, sB[140], fmaf(eay, sB[142], sB[144]+sB[146]));
      float v1B = fmaf(eax, sB[141], fmaf(eay, sB[143], sB[145]+sB[147]));
      #pragma unroll
      for (int f=0;f<8;f++){
        accA = fmaf(xs[f], r2a[f], accA);   accB = fmaf(xs[f], r2b[f], accB);
        v0A  = fmaf(xs[f], sA[104+f], v0A); v0B  = fmaf(xs[f], sB[104+f], v0B);
        v1A  = fmaf(xs[f], sA[112+f], v1A); v1B  = fmaf(xs[f], sB[112+f], v1B);
      }
      accA = fmaf(eax, t0a, fmaf(eay, t1a, accA));
      accB = fmaf(eax, t0b, fmaf(eay, t1b, accB));
      const float peA = __expf(accA * 0.08838834764831845f);
      const float peB = __expf(accB * 0.08838834764831845f);
      denA += peA; n0A = fmaf(peA, v0A, n0A); n1A = fmaf(peA, v1A, n1A);
      denB += peB; n0B = fmaf(peB, v0B, n0B); n1B = fmaf(peB, v1B, n1B);
    }
    const float invA = 1.0f/(denA + 1e-16f);
    const float invB = 1.0f/(denB + 1e-16f);
    float s0a = fmaf(n0A, invA, sA[148]), s1a = fmaf(n1A, invA, sA[149]);
    float s0b = fmaf(n0B, invB, sB[148]), s1b = fmaf(n1B, invB, sB[149]);
    #pragma unroll
    for (int f=0;f<8;f++){
      s0a = fmaf(xd[f], sA[120+f], s0a); s1a = fmaf(xd[f], sA[128+f], s1a);
      s0b = fmaf(xd[f], sB[120+f], s0b); s1b = fmaf(xd[f], sB[128+f], s1b);
    }
    const int baseA = c_aggoff[dt] + (0*c_cnt[dt] + c_slot[t])*N + n;
    const int baseB = c_aggoff[dt] + (1*c_cnt[dt] + c_slot[t])*N + n;
    ((float2*)g)[baseA] = make_float2(s0a, s1a);
    ((float2*)g)[baseB] = make_float2(s0b, s1b);
    #pragma unroll
    for (int h=0;h<64;h++){
      float za = fmaf(s0a, wlb[h], fmaf(s1a, wlb[64+h], wlb[128+h]));
      float zb = fmaf(s0b, wlb[h], fmaf(s1b, wlb[64+h], wlb[128+h]));
      lmin = fminf(lmin, fminf(za,zb)); lmax = fmaxf(lmax, fmaxf(za,zb));
    }
  }
  #pragma unroll
  for (int m=32;m>=1;m>>=1){
    lmin = fminf(lmin, __shfl_xor(lmin,m));
    lmax = fmaxf(lmax, __shfl_xor(lmax,m));
  }
  const int wv = tid>>6;
  if ((tid&63)==0){ smin[wv]=lmin; smax[wv]=lmax; }
  __syncthreads();
  if (tid==0){
    float mn = fminf(fminf(smin[0],smin[1]), fminf(smin[2],smin[3]));
    float mx = fmaxf(fmaxf(smax[0],smax[1]), fmaxf(smax[2],smax[3]));
    atomicMin(&mm[0], encf(mn));
    atomicMax(&mm[1], encf(mx));
  }
}

// ---- final v6: R7's proven orientation (lane=h/o, scalar per-lane nrm,
// readlane broadcast, weights resident as 16 named float4). 64 rows/wave,
// 4-row ILP, elufast at all per-row elu sites. Coalesced 256B stores. ----
#define MVC(W, C, B) \
  acca = fmaf(RL(na,(B)), W.C, acca); accb = fmaf(RL(nb,(B)), W.C, accb); \
  accc = fmaf(RL(nc,(B)), W.C, accc); accd = fmaf(RL(nd,(B)), W.C, accd);
#define MV4(W, B) MVC(W,x,(B)) MVC(W,y,(B)+1) MVC(W,z,(B)+2) MVC(W,w,(B)+3)

__global__ __launch_bounds__(256) void k_final(
    const float* __restrict__ g, const unsigned* __restrict__ mm,
    const float* __restrict__ Wl, const float* __restrict__ bl,
    const float* __restrict__ Wfc, const float* __restrict__ bfc,
    const float* __restrict__ Wl2, const float* __restrict__ bl2,
    float* __restrict__ out){
  const int gw = blockIdx.x*4 + (threadIdx.x>>6);   // global wave id, 64 rows each
  const int lane = threadIdx.x & 63;
  int nt, wo;
  if (gw < 375)       { nt=0; wo=0; }
  else if (gw < 4125) { nt=1; wo=375; }
  else if (gw < 6000) { nt=2; wo=4125; }
  else                { nt=3; wo=6000; }
  const int R = c_aggrows[nt];
  const int r0 = (gw - wo)*64;   // row base (all nt sizes are x64)
  // per-lane (h=lane / o=lane) weights
  const float wl0 = Wl[lane], wl1 = Wl[64+lane], blv = bl[lane];
  const float bfcv = bfc[nt*64+lane];
  const float wl20 = Wl2[lane], wl21 = Wl2[64+lane], bl2v = bl2[lane];
  const float* __restrict__ W = Wfc + (size_t)nt*4096;   // W[h][o], o=lane
  const float4 w0 = make_float4(W[0*64+lane], W[1*64+lane], W[2*64+lane], W[3*64+lane]);
  const float4 w1 = make_float4(W[4*64+lane], W[5*64+lane], W[6*64+lane], W[7*64+lane]);
  const float4 w2 = make_float4(W[8*64+lane], W[9*64+lane], W[10*64+lane], W[11*64+lane]);
  const float4 w3 = make_float4(W[12*64+lane], W[13*64+lane], W[14*64+lane], W[15*64+lane]);
  const float4 w4 = make_float4(W[16*64+lane], W[17*64+lane], W[18*64+lane], W[19*64+lane]);
  const float4 w5 = make_float4(W[20*64+lane], W[21*64+lane], W[22*64+lane], W[23*64+lane]);
  const float4 w6 = make_float4(W[24*64+lane], W[25*64+lane], W[26*64+lane], W[27*64+lane]);
  const float4 w7 = make_float4(W[28*64+lane], W[29*64+lane], W[30*64+lane], W[31*64+lane]);
  const float4 w8 = make_float4(W[32*64+lane], W[33*64+lane], W[34*64+lane], W[35*64+lane]);
  const float4 w9 = make_float4(W[36*64+lane], W[37*64+lane], W[38*64+lane], W[39*64+lane]);
  const float4 wA = make_float4(W[40*64+lane], W[41*64+lane], W[42*64+lane], W[43*64+lane]);
  const float4 wB = make_float4(W[44*64+lane], W[45*64+lane], W[46*64+lane], W[47*64+lane]);
  const float4 wC = make_float4(W[48*64+lane], W[49*64+lane], W[50*64+lane], W[51*64+lane]);
  const float4 wD = make_float4(W[52*64+lane], W[53*64+lane], W[54*64+lane], W[55*64+lane]);
  const float4 wE = make_float4(W[56*64+lane], W[57*64+lane], W[58*64+lane], W[59*64+lane]);
  const float4 wF = make_float4(W[60*64+lane], W[61*64+lane], W[62*64+lane], W[63*64+lane]);
  const float zmin = decf(mm[0]), zmax = decf(mm[1]);
  const float rmin = 0.1f*eluf(zmin);
  const float rmax = 0.9f + 0.1f*eluf(zmax);
  const float s2 = 2.0f/(rmax - rmin + 1e-5f);
  const float cc = fmaf(-rmin, s2, -1.0f);      // nrm = elu(z)*s2 + cc
  // row data: lane r holds row r0+r's (g0,g1)
  const float2 gv = ((const float2*)g)[c_aggoff[nt] + r0 + lane];
  const float gx = gv.x, gy = gv.y;
  float* __restrict__ o1 = out + ((size_t)c_outoff[nt] + r0)*64 + lane;
  float* __restrict__ o2 = o1 + (size_t)R*64;
  for (int r=0; r<64; r+=4){
    // 4 rows' scalars broadcast
    const float g0a=RL(gx,r+0), g1a=RL(gy,r+0);
    const float g0b=RL(gx,r+1), g1b=RL(gy,r+1);
    const float g0c=RL(gx,r+2), g1c=RL(gy,r+2);
    const float g0d=RL(gx,r+3), g1d=RL(gy,r+3);
    // nrm scalar per lane (h=lane) for each row
    const float na = fmaf(elufast(fmaf(g0a, wl0, fmaf(g1a, wl1, blv))), s2, cc);
    const float nb = fmaf(elufast(fmaf(g0b, wl0, fmaf(g1b, wl1, blv))), s2, cc);
    const float nc = fmaf(elufast(fmaf(g0c, wl0, fmaf(g1c, wl1, blv))), s2, cc);
    const float nd = fmaf(elufast(fmaf(g0d, wl0, fmaf(g1d, wl1, blv))), s2, cc);
    // matvec: acc_o = bfc[o] + sum_h nrm_h * W[h][o]  (o=lane)
    float acca = bfcv, accb = bfcv, accc = bfcv, accd = bfcv;
    MV4(w0,0)  MV4(w1,4)  MV4(w2,8)  MV4(w3,12)
    MV4(w4,16) MV4(w5,20) MV4(w6,24) MV4(w7,28)
    MV4(w8,32) MV4(w9,36) MV4(wA,40) MV4(wB,44)
    MV4(wC,48) MV4(wD,52) MV4(wE,56) MV4(wF,60)
    // elu + half-sum reduce (lanes 0-31 -> h0, lanes 32-63 -> h1)
    float sa = elufast(acca), sb = elufast(accb), sc = elufast(accc), sd = elufast(accd);
    sa += __shfl_xor(sa,16); sb += __shfl_xor(sb,16); sc += __shfl_xor(sc,16); sd += __shfl_xor(sd,16);
    sa += __shfl_xor(sa,8);  sb += __shfl_xor(sb,8);  sc += __shfl_xor(sc,8);  sd += __shfl_xor(sd,8);
    sa += __shfl_xor(sa,4);  sb += __shfl_xor(sb,4);  sc += __shfl_xor(sc,4);  sd += __shfl_xor(sd,4);
    sa += __shfl_xor(sa,2);  sb += __shfl_xor(sb,2);  sc += __shfl_xor(sc,2);  sd += __shfl_xor(sd,2);
    sa += __shfl_xor(sa,1);  sb += __shfl_xor(sb,1);  sc += __shfl_xor(sc,1);  sd += __shfl_xor(sd,1);
    const float fa = elufast(fmaf(RL(sa,0), wl20, fmaf(RL(sa,32), wl21, bl2v)));
    const float fb = elufast(fmaf(RL(sb,0), wl20, fmaf(RL(sb,32), wl21, bl2v)));
    const float fc = elufast(fmaf(RL(sc,0), wl20, fmaf(RL(sc,32), wl21, bl2v)));
    const float fd = elufast(fmaf(RL(sd,0), wl20, fmaf(RL(sd,32), wl21, bl2v)));
    o1[(size_t)(r+0)*64] = fa; o2[(size_t)(r+0)*64] = fa;
    o1[(size_t)(r+1)*64] = fb; o2[(size_t)(r+1)*64] = fb;
    o1[(size_t)(r+2)*64] = fc; o2[(size_t)(r+2)*64] = fc;
    o1[(size_t)(r+3)*64] = fd; o2[(size_t)(r+3)*64] = fd;
  }
}

extern "C" void kernel_launch(void* const* d_in, const int* in_sizes, int n_in,
                              void* d_out, int out_size, void* d_ws, size_t ws_size,
                              hipStream_t stream) {
  const float* xSB = (const float*)d_in[0];
  const float* cSB = (const float*)d_in[1];
  const float* xPQ = (const float*)d_in[2];
  const float* cPQ = (const float*)d_in[3];
  const float* xPV = (const float*)d_in[4];
  const float* cPV = (const float*)d_in[5];
  const float* xNB = (const float*)d_in[6];
  const float* cNB = (const float*)d_in[7];
  const int*   eidx = (const int*)d_in[8];
  const float* eattr= (const float*)d_in[9];
  const float* Wq = (const float*)d_in[10];
  const float* bq = (const float*)d_in[11];
  const float* Wk = (const float*)d_in[12];
  const float* bk = (const float*)d_in[13];
  const float* Wv = (const float*)d_in[14];
  const float* bv = (const float*)d_in[15];
  const float* We = (const float*)d_in[16];
  const float* be = (const float*)d_in[17];
  const float* Ws = (const float*)d_in[18];
  const float* bs = (const float*)d_in[19];
  const float* Wl = (const float*)d_in[20];
  const float* bl = (const float*)d_in[21];
  const float* Wfc= (const float*)d_in[22];
  const float* bfc= (const float*)d_in[23];
  const float* Wl2= (const float*)d_in[24];
  const float* bl2= (const float*)d_in[25];

  float* ws    = (float*)d_ws;
  float* xall  = ws + 0;                    // 488000 f
  float* par   = ws + 488000;               // 4800 f
  int* gs2     = (int*)(ws + 492800);       // 240015 i
  int* glen    = (int*)(ws + 732815);       // 240015 i
  int* gcnt    = (int*)(ws + 972830);       // 240 i
  int* gofs    = (int*)(ws + 973070);       // 240 i
  int* gcur    = (int*)(ws + 973310);       // 240 i
  unsigned* mm = (unsigned*)(ws + 973550);  // 2
  unsigned* ebuf = (unsigned*)(ws + 973552);// 2250000 u32 (stage-1 buckets)
  float* g     = ws + 973552;               // 960000 f (aliases ebuf; ebuf dead after k_tsort)
  uint2* erec  = (uint2*)(ws + 3223552);    // 2250000 uint2 (even offset -> 8B aligned)
  // end: 7723552 floats ~= 30.9 MB

  hipMemsetAsync(gcnt, 0, 240*sizeof(int), stream);
  hipMemsetAsync(mm,   0xFF, 4, stream);
  hipMemsetAsync(mm+1, 0x00, 4, stream);

  k_build_x<<<(61000+255)/256, 256, 0, stream>>>(xSB,cSB,xPQ,cPQ,xPV,cPV,xNB,cNB, xall);
  k_params<<<30, 128, 0, stream>>>(Wq,bq,Wk,bk,Wv,bv,We,be,Ws,bs, par);
  dim3 gb(8, 15);
  k_count<<<gb, 1024, 0, stream>>>(eidx, gcnt);
  k_scan<<<1, 64, 0, stream>>>(gcnt, gofs, gcur);
  k_scatter<<<gb, 1024, 0, stream>>>(eidx, gcur, ebuf);
  k_tsort<<<240, 1024, 0, stream>>>(ebuf, eidx, eattr, gofs, gcnt, erec, gs2, glen);
  dim3 gg((30000+255)/256, 15);
  k_gather<<<gg, 256, 0, stream>>>(gs2, glen, erec, xall, par, Wl, bl, g, mm);
  k_final<<<1875, 256, 0, stream>>>(g, mm, Wl, bl, Wfc, bfc, Wl2, bl2, (float*)d_out);
}

// Round 11
// 274.081 us; speedup vs baseline: 1.9771x; 1.2828x over previous
//
#include <hip/hip_runtime.h>
#include <hip/hip_fp16.h>
#include <math.h>

#define NE 150000

// type ids: SB=0 PQ=1 PV=2 NB=3
__constant__ int c_stype[15] = {2,0,0,2,3,1,0,1,3,1,2,3,2,1,3};
__constant__ int c_dtype[15] = {0,1,3,1,1,3,2,0,0,2,3,2,2,1,3};
__constant__ int c_slot[15]  = {0,0,0,1,2,1,0,1,2,1,2,2,3,3,3};
__constant__ int c_N[4]      = {4000,30000,15000,12000};
__constant__ int c_xoff[4]   = {0,4000,34000,49000};
__constant__ int c_cnt[4]    = {3,4,4,4};
__constant__ int c_aggoff[4] = {0,24000,264000,384000};
__constant__ int c_outoff[4] = {0,48000,528000,768000};
__constant__ int c_aggrows[4]= {24000,240000,120000,96000};
// bucket id prefix: tiles per type = ceil(N[dtype]/1024)
__constant__ int c_tprefix[16] = {0,4,34,46,76,106,118,133,137,141,156,168,183,198,228,240};
// per-type row-meta offsets (stride N+1, slack unused)
__constant__ int c_toff2[15] = {0,4001,34002,46003,76004,106005,118006,133007,137008,141009,156010,168011,183012,198013,228014};

typedef _Float16 f16x8 __attribute__((ext_vector_type(8)));
typedef float f32x4 __attribute__((ext_vector_type(4)));

__device__ __forceinline__ float eluf(float x){ return x > 0.0f ? x : expm1f(x); }
__device__ __forceinline__ float elufast(float x){ return x > 0.0f ? x : __expf(x)-1.0f; }
__device__ __forceinline__ unsigned encf(float f){ unsigned u=__float_as_uint(f); return (u&0x80000000u)? ~u : (u|0x80000000u); }
__device__ __forceinline__ float decf(unsigned u){ return __uint_as_float((u&0x80000000u)? (u^0x80000000u) : ~u); }
__device__ __forceinline__ float RL(float v, int l){ return __uint_as_float(__builtin_amdgcn_readlane(__float_as_uint(v), l)); }

// ---- build x = concat(x_nt, c_nt) for all 61000 nodes ----
__global__ __launch_bounds__(256) void k_build_x(
    const float* __restrict__ xSB, const float* __restrict__ cSB,
    const float* __restrict__ xPQ, const float* __restrict__ cPQ,
    const float* __restrict__ xPV, const float* __restrict__ cPV,
    const float* __restrict__ xNB, const float* __restrict__ cNB,
    float* __restrict__ xall){
  int n = blockIdx.x*256 + threadIdx.x;
  if (n >= 61000) return;
  const float *xp, *cp; int local;
  if (n < 4000)      { xp=xSB; cp=cSB; local=n; }
  else if (n < 34000){ xp=xPQ; cp=cPQ; local=n-4000; }
  else if (n < 49000){ xp=xPV; cp=cPV; local=n-34000; }
  else               { xp=xNB; cp=cNB; local=n-49000; }
  float4 a = ((const float4*)xp)[local];
  float4 b = ((const float4*)cp)[local];
  ((float4*)xall)[n*2+0] = a;
  ((float4*)xall)[n*2+1] = b;
}

__device__ __forceinline__ float dot128(const float* __restrict__ a, const float* __restrict__ b){
  const float4* a4 = (const float4*)a; const float4* b4 = (const float4*)b;
  float s = 0.f;
  #pragma unroll
  for (int h=0; h<32; h++){
    float4 A=a4[h], B=b4[h];
    s = fmaf(A.x,B.x,s); s = fmaf(A.y,B.y,s); s = fmaf(A.z,B.z,s); s = fmaf(A.w,B.w,s);
  }
  return s;
}
__device__ __forceinline__ void halfsum(const float* __restrict__ a, float& s0, float& s1){
  const float4* a4 = (const float4*)a;
  float x0=0.f, x1=0.f;
  #pragma unroll
  for (int h=0; h<16; h++){ float4 A=a4[h]; x0 += A.x+A.y+A.z+A.w; }
  #pragma unroll
  for (int h=16; h<32; h++){ float4 A=a4[h]; x1 += A.x+A.y+A.z+A.w; }
  s0=x0; s1=x1;
}

// ---- derive per-conv small params (160 floats per conv) ----
__global__ __launch_bounds__(128) void k_params(
    const float* __restrict__ Wq, const float* __restrict__ bq,
    const float* __restrict__ Wk, const float* __restrict__ bk,
    const float* __restrict__ Wv, const float* __restrict__ bv,
    const float* __restrict__ We, const float* __restrict__ be,
    const float* __restrict__ Ws, const float* __restrict__ bs,
    float* __restrict__ par){
  const int c = blockIdx.x, tid = threadIdx.x;
  const float* wq = Wq + (size_t)c*1024;
  const float* wk = Wk + (size_t)c*1024;
  const float* wv = Wv + (size_t)c*1024;
  const float* ws = Ws + (size_t)c*1024;
  const float* we = We + (size_t)c*256;
  const float* vbq = bq + (size_t)c*128;
  const float* vbk = bk + (size_t)c*128;
  const float* vbv = bv + (size_t)c*128;
  const float* vbe = be + (size_t)c*128;
  const float* vbs = bs + (size_t)c*128;
  float* P = par + (size_t)c*160;
  if (tid < 64){
    int fd = tid>>3, fs = tid&7;
    P[tid] = dot128(wq + fd*128, wk + fs*128);
    return;
  }
  const int job = tid - 64, grp = job>>3, f = job&7;
  if (grp==0) P[64+f] = dot128(wq + f*128, vbk);
  else if (grp==1) P[72+f] = dot128(wk + f*128, vbq);
  else if (grp==2) P[80+f] = dot128(wq + f*128, we);
  else if (grp==3) P[88+f] = dot128(wq + f*128, we+128);
  else if (grp==4) P[96+f] = dot128(wq + f*128, vbe);
  else if (grp==5){ float s0,s1; halfsum(wv + f*128, s0,s1); P[104+f]=s0; P[112+f]=s1; }
  else if (grp==6){ float s0,s1; halfsum(ws + f*128, s0,s1); P[120+f]=s0; P[128+f]=s1; }
  else {
    if (f==0){ P[136] = dot128(vbq, vbk);
               float a,b; halfsum(vbs, a,b); P[148]=a; P[149]=b; }
    else if (f==1) P[137] = dot128(vbq, we);
    else if (f==2) P[138] = dot128(vbq, we+128);
    else if (f==3) P[139] = dot128(vbq, vbe);
    else if (f==4){ float a=0.f,b=0.f; for(int h=0;h<64;h++){a+=we[h]; b+=we[64+h];} P[140]=a; P[141]=b; }
    else if (f==5){ float a=0.f,b=0.f; for(int h=0;h<64;h++){a+=we[128+h]; b+=we[192+h];} P[142]=a; P[143]=b; }
    else if (f==6){ float a,b; halfsum(vbv, a,b); P[144]=a; P[145]=b; }
    else          { float a,b; halfsum(vbe, a,b); P[146]=a; P[147]=b; }
  }
}

#define CHUNK 18750

// ---- stage 1a: per-type histogram of dst>>10 (each edge read once) ----
__global__ __launch_bounds__(1024) void k_count(const int* __restrict__ eidx,
                                                int* __restrict__ gcnt){
  const int t = blockIdx.y;
  __shared__ int cnt[32];
  if (threadIdx.x < 32) cnt[threadIdx.x] = 0;
  __syncthreads();
  const int* __restrict__ dstp = eidx + (size_t)(t*2+1)*NE;
  const int e0 = blockIdx.x*CHUNK, e1 = min(NE, e0+CHUNK);
  for (int e=e0+threadIdx.x; e<e1; e+=1024) atomicAdd(&cnt[dstp[e]>>10], 1);
  __syncthreads();
  if (threadIdx.x < 32 && cnt[threadIdx.x] > 0)
    atomicAdd(&gcnt[c_tprefix[t] + threadIdx.x], cnt[threadIdx.x]);
}

// ---- stage 1b: per-type exclusive scan of bucket counts ----
__global__ void k_scan(const int* __restrict__ gcnt, int* __restrict__ gofs,
                       int* __restrict__ gcur){
  const int t = threadIdx.x;
  if (t >= 15) return;
  const int b0 = c_tprefix[t], b1 = c_tprefix[t+1];
  int run = t*NE;
  for (int b=b0; b<b1; b++){ gofs[b]=run; gcur[b]=run; run += gcnt[b]; }
}

// ---- stage 1c: scatter packed (eid<<10)|dl into tile buckets ----
__global__ __launch_bounds__(1024) void k_scatter(const int* __restrict__ eidx,
    int* __restrict__ gcur, unsigned* __restrict__ ebuf){
  const int t = blockIdx.y;
  __shared__ int lcnt[32], lbase[32];
  if (threadIdx.x < 32) lcnt[threadIdx.x] = 0;
  __syncthreads();
  const int* __restrict__ dstp = eidx + (size_t)(t*2+1)*NE;
  const int e0 = blockIdx.x*CHUNK, e1 = min(NE, e0+CHUNK);
  for (int e=e0+threadIdx.x; e<e1; e+=1024) atomicAdd(&lcnt[dstp[e]>>10], 1);
  __syncthreads();
  if (threadIdx.x < 32){
    int cchk = lcnt[threadIdx.x];
    lbase[threadIdx.x] = cchk > 0 ? atomicAdd(&gcur[c_tprefix[t]+threadIdx.x], cchk) : 0;
  }
  __syncthreads();
  if (threadIdx.x < 32) lcnt[threadIdx.x] = 0;
  __syncthreads();
  for (int e=e0+threadIdx.x; e<e1; e+=1024){
    const int d = dstp[e];
    const int tile = d>>10, dl = d&1023;
    const int pos = lbase[tile] + atomicAdd(&lcnt[tile], 1);
    ebuf[pos] = ((unsigned)e<<10) | (unsigned)dl;
  }
}

// ---- stage 2: per-tile row sort. One block per tile bucket; reads ONLY its
// own bucket (sequential). Pass 1: row histogram + scan -> gs2/glen.
// Pass 2: scatter {src, f16x2 ea} into row-sorted erec. ----
__global__ __launch_bounds__(1024) void k_tsort(
    const unsigned* __restrict__ ebuf, const int* __restrict__ eidx,
    const float* __restrict__ eattr,
    const int* __restrict__ gofs, const int* __restrict__ gcnt,
    uint2* __restrict__ erec, int* __restrict__ gs2, int* __restrict__ glen){
  const int b = blockIdx.x;
  int t = 0;
  while (b >= c_tprefix[t+1]) ++t;
  const int tile = b - c_tprefix[t];
  const int dt = c_dtype[t];
  const int N = c_N[dt];
  const int nbase = tile << 10;
  const int tileN = min(1024, N - nbase);
  const int tid = threadIdx.x;
  const int lane = tid & 63, wid = tid >> 6;

  __shared__ int cnt[1024];
  __shared__ int wsum[16];

  cnt[tid] = 0;
  __syncthreads();
  const int start = gofs[b], count = gcnt[b];
  for (int k=tid; k<count; k+=1024) atomicAdd(&cnt[ebuf[start+k] & 1023u], 1);
  __syncthreads();
  const int v = cnt[tid];
  int inc = v;
  #pragma unroll
  for (int off=1; off<64; off<<=1){ int u = __shfl_up(inc, off); if (lane>=off) inc += u; }
  if (lane==63) wsum[wid] = inc;
  __syncthreads();
  if (tid==0){ int r=0; for (int k=0;k<16;k++){ int x=wsum[k]; wsum[k]=r; r+=x; } }
  __syncthreads();
  const int pref = wsum[wid] + inc - v;  // exclusive prefix within bucket
  if (tid < tileN){
    gs2 [c_toff2[t] + nbase + tid] = start + pref;
    glen[c_toff2[t] + nbase + tid] = v;
  }
  cnt[tid] = pref;
  __syncthreads();

  const int* __restrict__ srcp = eidx + (size_t)(t*2)*NE;
  const float2* __restrict__ ea2 = (const float2*)eattr + (size_t)t*NE;
  for (int k=tid; k<count; k+=1024){
    const unsigned u = ebuf[start+k];
    const int dl = u & 1023u;
    const int eid = u >> 10;
    const int pos = start + atomicAdd(&cnt[dl], 1);
    const float2 ea = ea2[eid];
    __half2 h2 = __floats2half2_rn(ea.x, ea.y);
    erec[pos] = make_uint2((unsigned)srcp[eid], *(unsigned*)&h2);
  }
}

// ---- gather: per (type,node) walk sorted run ONCE, both layers' convs in
// registers. Zero LDS/atomics in the loop. Fuses softmax, skip, minmax.
__global__ __launch_bounds__(256) void k_gather(
    const int* __restrict__ gs2, const int* __restrict__ glen,
    const uint2* __restrict__ erec,
    const float* __restrict__ xall, const float* __restrict__ par,
    const float* __restrict__ Wl, const float* __restrict__ bl,
    float* __restrict__ g, unsigned* __restrict__ mm){
  const int t = blockIdx.y;
  const int dt = c_dtype[t], st = c_stype[t];
  const int N = c_N[dt];
  if (blockIdx.x*256 >= N) return;
  __shared__ float sA[160], sB[160];
  __shared__ float wlb[192];
  __shared__ float smin[4], smax[4];
  const int tid = threadIdx.x;
  if (tid < 160){ sA[tid] = par[(size_t)t*160 + tid]; sB[tid] = par[(size_t)(15+t)*160 + tid]; }
  if (tid < 192) wlb[tid] = (tid<128)? Wl[tid] : bl[tid-128];
  __syncthreads();
  const int n = blockIdx.x*256 + tid;
  const bool valid = n < N;
  float lmin = 3.4e38f, lmax = -3.4e38f;
  if (valid){
    const float4* xdp = (const float4*)(xall + (size_t)(c_xoff[dt]+n)*8);
    float4 b0v = xdp[0], b1v = xdp[1];
    float xd[8] = {b0v.x,b0v.y,b0v.z,b0v.w,b1v.x,b1v.y,b1v.z,b1v.w};
    float r2a[8], r2b[8];
    #pragma unroll
    for (int fs=0; fs<8; fs++){
      float a = sA[72+fs], bb = sB[72+fs];
      #pragma unroll
      for (int fd=0; fd<8; fd++){ a = fmaf(xd[fd], sA[fd*8+fs], a); bb = fmaf(xd[fd], sB[fd*8+fs], bb); }
      r2a[fs]=a; r2b[fs]=bb;
    }
    float t0a=sA[137], t1a=sA[138], tba=sA[139], u0a=sA[136];
    float t0b=sB[137], t1b=sB[138], tbb=sB[139], u0b=sB[136];
    #pragma unroll
    for (int f=0;f<8;f++){
      t0a = fmaf(xd[f], sA[80+f], t0a);  t0b = fmaf(xd[f], sB[80+f], t0b);
      t1a = fmaf(xd[f], sA[88+f], t1a);  t1b = fmaf(xd[f], sB[88+f], t1b);
      tba = fmaf(xd[f], sA[96+f], tba);  tbb = fmaf(xd[f], sB[96+f], tbb);
      u0a = fmaf(xd[f], sA[64+f], u0a);  u0b = fmaf(xd[f], sB[64+f], u0b);
    }
    const float accda = u0a + tba, accdb = u0b + tbb;
    const int o = c_toff2[t];
    const int js = gs2[o+n], je = js + glen[o+n];
    float denA=0.f, n0A=0.f, n1A=0.f;
    float denB=0.f, n0B=0.f, n1B=0.f;
    for (int j=js; j<je; j++){
      const uint2 rec = erec[j];
      const int src = (int)rec.x;
      const __half2 h2 = *(const __half2*)&rec.y;
      const float eax = __low2float(h2), eay = __high2float(h2);
      const float4* xsp = (const float4*)(xall + (size_t)(c_xoff[st]+src)*8);
      float4 a0v = xsp[0], a1v = xsp[1];
      float xs[8] = {a0v.x,a0v.y,a0v.z,a0v.w,a1v.x,a1v.y,a1v.z,a1v.w};
      float accA = accda, accB = accdb;
      float v0A = fmaf(eax, sA[140], fmaf(eay, sA[142], sA[144]+sA[146]));
      float v1A = fmaf(eax, sA[141], fmaf(eay, sA[143], sA[145]+sA[147]));
      float v0B = fmaf(eax, sB[140], fmaf(eay, sB[142], sB[144]+sB[146]));
      float v1B = fmaf(eax, sB[141], fmaf(eay, sB[143], sB[145]+sB[147]));
      #pragma unroll
      for (int f=0;f<8;f++){
        accA = fmaf(xs[f], r2a[f], accA);   accB = fmaf(xs[f], r2b[f], accB);
        v0A  = fmaf(xs[f], sA[104+f], v0A); v0B  = fmaf(xs[f], sB[104+f], v0B);
        v1A  = fmaf(xs[f], sA[112+f], v1A); v1B  = fmaf(xs[f], sB[112+f], v1B);
      }
      accA = fmaf(eax, t0a, fmaf(eay, t1a, accA));
      accB = fmaf(eax, t0b, fmaf(eay, t1b, accB));
      const float peA = __expf(accA * 0.08838834764831845f);
      const float peB = __expf(accB * 0.08838834764831845f);
      denA += peA; n0A = fmaf(peA, v0A, n0A); n1A = fmaf(peA, v1A, n1A);
      denB += peB; n0B = fmaf(peB, v0B, n0B); n1B = fmaf(peB, v1B, n1B);
    }
    const float invA = 1.0f/(denA + 1e-16f);
    const float invB = 1.0f/(denB + 1e-16f);
    float s0a = fmaf(n0A, invA, sA[148]), s1a = fmaf(n1A, invA, sA[149]);
    float s0b = fmaf(n0B, invB, sB[148]), s1b = fmaf(n1B, invB, sB[149]);
    #pragma unroll
    for (int f=0;f<8;f++){
      s0a = fmaf(xd[f], sA[120+f], s0a); s1a = fmaf(xd[f], sA[128+f], s1a);
      s0b = fmaf(xd[f], sB[120+f], s0b); s1b = fmaf(xd[f], sB[128+f], s1b);
    }
    const int baseA = c_aggoff[dt] + (0*c_cnt[dt] + c_slot[t])*N + n;
    const int baseB = c_aggoff[dt] + (1*c_cnt[dt] + c_slot[t])*N + n;
    ((float2*)g)[baseA] = make_float2(s0a, s1a);
    ((float2*)g)[baseB] = make_float2(s0b, s1b);
    #pragma unroll
    for (int h=0;h<64;h++){
      float za = fmaf(s0a, wlb[h], fmaf(s1a, wlb[64+h], wlb[128+h]));
      float zb = fmaf(s0b, wlb[h], fmaf(s1b, wlb[64+h], wlb[128+h]));
      lmin = fminf(lmin, fminf(za,zb)); lmax = fmaxf(lmax, fmaxf(za,zb));
    }
  }
  #pragma unroll
  for (int m=32;m>=1;m>>=1){
    lmin = fminf(lmin, __shfl_xor(lmin,m));
    lmax = fmaxf(lmax, __shfl_xor(lmax,m));
  }
  const int wv = tid>>6;
  if ((tid&63)==0){ smin[wv]=lmin; smax[wv]=lmax; }
  __syncthreads();
  if (tid==0){
    float mn = fminf(fminf(smin[0],smin[1]), fminf(smin[2],smin[3]));
    float mx = fmaxf(fmaxf(smax[0],smax[1]), fmaxf(smax[2],smax[3]));
    atomicMin(&mm[0], encf(mn));
    atomicMax(&mm[1], encf(mx));
  }
}

// ---- final v7: f16 MFMA matvec. Per wave: 64 rows, M=N=K=64 ->
// 32x mfma_f32_16x16x32_f16. A: row=l&15, k=8*(l>>4)+j. B: col=l&15,
// k=8*(l>>4)+j. D (m89-verified): col=l&15, row=4*(l>>4)+reg.
// Epilogue: elu + 16-lane shfl half-sums, per-row readlane, coalesced stores.
__global__ __launch_bounds__(256, 1) void k_final(
    const float* __restrict__ g, const unsigned* __restrict__ mm,
    const float* __restrict__ Wl, const float* __restrict__ bl,
    const float* __restrict__ Wfc, const float* __restrict__ bfc,
    const float* __restrict__ Wl2, const float* __restrict__ bl2,
    float* __restrict__ out){
  const int gw = blockIdx.x*4 + (threadIdx.x>>6);   // global wave id, 64 rows each
  const int l  = threadIdx.x & 63;
  const int lr = l & 15, lg = l >> 4;
  int nt, wo;
  if (gw < 375)       { nt=0; wo=0; }
  else if (gw < 4125) { nt=1; wo=375; }
  else if (gw < 6000) { nt=2; wo=4125; }
  else                { nt=3; wo=6000; }
  const int R = c_aggrows[nt];
  const int r0 = (gw - wo)*64;   // row base (all nt sizes are x64)
  const float zmin = decf(mm[0]), zmax = decf(mm[1]);
  const float rmin = 0.1f*eluf(zmin);
  const float rmax = 0.9f + 0.1f*eluf(zmax);
  const float s2 = 2.0f/(rmax - rmin + 1e-5f);
  const float cc = fmaf(-rmin, s2, -1.0f);      // nrm = elu(z)*s2 + cc
  // Wl slices for A-build: h = kk*32 + lg*8 + j  (contiguous 8 per lane-group)
  float wl0v[2][8], wl1v[2][8], blv[2][8];
  #pragma unroll
  for (int kk=0; kk<2; kk++){
    const int hb = kk*32 + lg*8;
    const float4 a0 = *(const float4*)&Wl[hb],    a1 = *(const float4*)&Wl[hb+4];
    const float4 b0 = *(const float4*)&Wl[64+hb], b1 = *(const float4*)&Wl[64+hb+4];
    const float4 c0 = *(const float4*)&bl[hb],    c1 = *(const float4*)&bl[hb+4];
    wl0v[kk][0]=a0.x; wl0v[kk][1]=a0.y; wl0v[kk][2]=a0.z; wl0v[kk][3]=a0.w;
    wl0v[kk][4]=a1.x; wl0v[kk][5]=a1.y; wl0v[kk][6]=a1.z; wl0v[kk][7]=a1.w;
    wl1v[kk][0]=b0.x; wl1v[kk][1]=b0.y; wl1v[kk][2]=b0.z; wl1v[kk][3]=b0.w;
    wl1v[kk][4]=b1.x; wl1v[kk][5]=b1.y; wl1v[kk][6]=b1.z; wl1v[kk][7]=b1.w;
    blv[kk][0]=c0.x;  blv[kk][1]=c0.y;  blv[kk][2]=c0.z;  blv[kk][3]=c0.w;
    blv[kk][4]=c1.x;  blv[kk][5]=c1.y;  blv[kk][6]=c1.z;  blv[kk][7]=c1.w;
  }
  // B fragments (weights): bfrag[kk][ntl] holds W[kk*32+lg*8+j][ntl*16+lr]
  const float* __restrict__ W = Wfc + (size_t)nt*4096;
  f16x8 bfrag[2][4];
  #pragma unroll
  for (int kk=0; kk<2; kk++){
    #pragma unroll
    for (int ntl=0; ntl<4; ntl++){
      #pragma unroll
      for (int j=0; j<8; j++){
        const int h = kk*32 + lg*8 + j;
        bfrag[kk][ntl][j] = (_Float16)W[h*64 + ntl*16 + lr];
      }
    }
  }
  const float bf0 = bfc[nt*64 + lr],      bf1 = bfc[nt*64 + 16 + lr];
  const float bf2 = bfc[nt*64 + 32 + lr], bf3 = bfc[nt*64 + 48 + lr];
  const float2* __restrict__ g2p = (const float2*)g + c_aggoff[nt] + r0;
  float ph0[4][4], ph1[4][4];   // [mt][reg] half-sums (uniform within 16-lane group)
  #pragma unroll
  for (int mt=0; mt<4; mt++){
    // A fragments for 16 rows (rows mt*16 + lr)
    const float2 gv = g2p[mt*16 + lr];
    f16x8 af0, af1;
    #pragma unroll
    for (int j=0; j<8; j++){
      const float z0 = fmaf(gv.x, wl0v[0][j], fmaf(gv.y, wl1v[0][j], blv[0][j]));
      const float z1 = fmaf(gv.x, wl0v[1][j], fmaf(gv.y, wl1v[1][j], blv[1][j]));
      af0[j] = (_Float16)fmaf(elufast(z0), s2, cc);
      af1[j] = (_Float16)fmaf(elufast(z1), s2, cc);
    }
    f32x4 d0 = {0.f,0.f,0.f,0.f}, d1 = {0.f,0.f,0.f,0.f};
    f32x4 d2 = {0.f,0.f,0.f,0.f}, d3 = {0.f,0.f,0.f,0.f};
    d0 = __builtin_amdgcn_mfma_f32_16x16x32_f16(af0, bfrag[0][0], d0, 0,0,0);
    d1 = __builtin_amdgcn_mfma_f32_16x16x32_f16(af0, bfrag[0][1], d1, 0,0,0);
    d2 = __builtin_amdgcn_mfma_f32_16x16x32_f16(af0, bfrag[0][2], d2, 0,0,0);
    d3 = __builtin_amdgcn_mfma_f32_16x16x32_f16(af0, bfrag[0][3], d3, 0,0,0);
    d0 = __builtin_amdgcn_mfma_f32_16x16x32_f16(af1, bfrag[1][0], d0, 0,0,0);
    d1 = __builtin_amdgcn_mfma_f32_16x16x32_f16(af1, bfrag[1][1], d1, 0,0,0);
    d2 = __builtin_amdgcn_mfma_f32_16x16x32_f16(af1, bfrag[1][2], d2, 0,0,0);
    d3 = __builtin_amdgcn_mfma_f32_16x16x32_f16(af1, bfrag[1][3], d3, 0,0,0);
    // epilogue-1: elu + bias, half-sums over o, reduce over the 16 cols (lr)
    #pragma unroll
    for (int reg=0; reg<4; reg++){
      float p0 = elufast(d0[reg] + bf0) + elufast(d1[reg] + bf1);
      float p1 = elufast(d2[reg] + bf2) + elufast(d3[reg] + bf3);
      p0 += __shfl_xor(p0,1); p0 += __shfl_xor(p0,2); p0 += __shfl_xor(p0,4); p0 += __shfl_xor(p0,8);
      p1 += __shfl_xor(p1,1); p1 += __shfl_xor(p1,2); p1 += __shfl_xor(p1,4); p1 += __shfl_xor(p1,8);
      ph0[mt][reg] = p0; ph1[mt][reg] = p1;
    }
  }
  // epilogue-2: per row r, (h0,h1) live at lane ((r&15)>>2)*16, slot [r>>4][r&3]
  const float wl20 = Wl2[l], wl21 = Wl2[64+l], bl2v = bl2[l];
  float* __restrict__ o1 = out + ((size_t)c_outoff[nt] + r0)*64 + l;
  float* __restrict__ o2 = o1 + (size_t)R*64;
  #pragma unroll
  for (int r=0; r<64; r++){
    const int mt = r>>4, rt = r&15;
    const float h0r = RL(ph0[mt][rt&3], (rt>>2)<<4);
    const float h1r = RL(ph1[mt][rt&3], (rt>>2)<<4);
    const float f = elufast(fmaf(h0r, wl20, fmaf(h1r, wl21, bl2v)));
    o1[(size_t)r*64] = f;
    o2[(size_t)r*64] = f;
  }
}

extern "C" void kernel_launch(void* const* d_in, const int* in_sizes, int n_in,
                              void* d_out, int out_size, void* d_ws, size_t ws_size,
                              hipStream_t stream) {
  const float* xSB = (const float*)d_in[0];
  const float* cSB = (const float*)d_in[1];
  const float* xPQ = (const float*)d_in[2];
  const float* cPQ = (const float*)d_in[3];
  const float* xPV = (const float*)d_in[4];
  const float* cPV = (const float*)d_in[5];
  const float* xNB = (const float*)d_in[6];
  const float* cNB = (const float*)d_in[7];
  const int*   eidx = (const int*)d_in[8];
  const float* eattr= (const float*)d_in[9];
  const float* Wq = (const float*)d_in[10];
  const float* bq = (const float*)d_in[11];
  const float* Wk = (const float*)d_in[12];
  const float* bk = (const float*)d_in[13];
  const float* Wv = (const float*)d_in[14];
  const float* bv = (const float*)d_in[15];
  const float* We = (const float*)d_in[16];
  const float* be = (const float*)d_in[17];
  const float* Ws = (const float*)d_in[18];
  const float* bs = (const float*)d_in[19];
  const float* Wl = (const float*)d_in[20];
  const float* bl = (const float*)d_in[21];
  const float* Wfc= (const float*)d_in[22];
  const float* bfc= (const float*)d_in[23];
  const float* Wl2= (const float*)d_in[24];
  const float* bl2= (const float*)d_in[25];

  float* ws    = (float*)d_ws;
  float* xall  = ws + 0;                    // 488000 f
  float* par   = ws + 488000;               // 4800 f
  int* gs2     = (int*)(ws + 492800);       // 240015 i
  int* glen    = (int*)(ws + 732815);       // 240015 i
  int* gcnt    = (int*)(ws + 972830);       // 240 i
  int* gofs    = (int*)(ws + 973070);       // 240 i
  int* gcur    = (int*)(ws + 973310);       // 240 i
  unsigned* mm = (unsigned*)(ws + 973550);  // 2
  unsigned* ebuf = (unsigned*)(ws + 973552);// 2250000 u32 (stage-1 buckets)
  float* g     = ws + 973552;               // 960000 f (aliases ebuf; ebuf dead after k_tsort)
  uint2* erec  = (uint2*)(ws + 3223552);    // 2250000 uint2 (even offset -> 8B aligned)
  // end: 7723552 floats ~= 30.9 MB

  hipMemsetAsync(gcnt, 0, 240*sizeof(int), stream);
  hipMemsetAsync(mm,   0xFF, 4, stream);
  hipMemsetAsync(mm+1, 0x00, 4, stream);

  k_build_x<<<(61000+255)/256, 256, 0, stream>>>(xSB,cSB,xPQ,cPQ,xPV,cPV,xNB,cNB, xall);
  k_params<<<30, 128, 0, stream>>>(Wq,bq,Wk,bk,Wv,bv,We,be,Ws,bs, par);
  dim3 gb(8, 15);
  k_count<<<gb, 1024, 0, stream>>>(eidx, gcnt);
  k_scan<<<1, 64, 0, stream>>>(gcnt, gofs, gcur);
  k_scatter<<<gb, 1024, 0, stream>>>(eidx, gcur, ebuf);
  k_tsort<<<240, 1024, 0, stream>>>(ebuf, eidx, eattr, gofs, gcnt, erec, gs2, glen);
  dim3 gg((30000+255)/256, 15);
  k_gather<<<gg, 256, 0, stream>>>(gs2, glen, erec, xall, par, Wl, bl, g, mm);
  k_final<<<1875, 256, 0, stream>>>(g, mm, Wl, bl, Wfc, bfc, Wl2, bl2, (float*)d_out);
}

// Round 12
// 256.110 us; speedup vs baseline: 2.1158x; 1.0702x over previous
//
#include <hip/hip_runtime.h>
#include <hip/hip_fp16.h>
#include <math.h>

#define NE 150000

// type ids: SB=0 PQ=1 PV=2 NB=3
__constant__ int c_stype[15] = {2,0,0,2,3,1,0,1,3,1,2,3,2,1,3};
__constant__ int c_dtype[15] = {0,1,3,1,1,3,2,0,0,2,3,2,2,1,3};
__constant__ int c_slot[15]  = {0,0,0,1,2,1,0,1,2,1,2,2,3,3,3};
__constant__ int c_N[4]      = {4000,30000,15000,12000};
__constant__ int c_xoff[4]   = {0,4000,34000,49000};
__constant__ int c_cnt[4]    = {3,4,4,4};
__constant__ int c_aggoff[4] = {0,24000,264000,384000};
__constant__ int c_outoff[4] = {0,48000,528000,768000};
__constant__ int c_aggrows[4]= {24000,240000,120000,96000};
// bucket id prefix: tiles per type = ceil(N[dtype]/1024)
__constant__ int c_tprefix[16] = {0,4,34,46,76,106,118,133,137,141,156,168,183,198,228,240};
// per-type row-meta offsets (stride N+1, slack unused)
__constant__ int c_toff2[15] = {0,4001,34002,46003,76004,106005,118006,133007,137008,141009,156010,168011,183012,198013,228014};

typedef _Float16 f16x8 __attribute__((ext_vector_type(8)));
typedef float f32x4 __attribute__((ext_vector_type(4)));

__device__ __forceinline__ float eluf(float x){ return x > 0.0f ? x : expm1f(x); }
__device__ __forceinline__ float elufast(float x){ return x > 0.0f ? x : __expf(x)-1.0f; }
__device__ __forceinline__ unsigned encf(float f){ unsigned u=__float_as_uint(f); return (u&0x80000000u)? ~u : (u|0x80000000u); }
__device__ __forceinline__ float decf(unsigned u){ return __uint_as_float((u&0x80000000u)? (u^0x80000000u) : ~u); }
__device__ __forceinline__ float RL(float v, int l){ return __uint_as_float(__builtin_amdgcn_readlane(__float_as_uint(v), l)); }

// ---- build x = concat(x_nt, c_nt) for all 61000 nodes ----
__global__ __launch_bounds__(256) void k_build_x(
    const float* __restrict__ xSB, const float* __restrict__ cSB,
    const float* __restrict__ xPQ, const float* __restrict__ cPQ,
    const float* __restrict__ xPV, const float* __restrict__ cPV,
    const float* __restrict__ xNB, const float* __restrict__ cNB,
    float* __restrict__ xall){
  int n = blockIdx.x*256 + threadIdx.x;
  if (n >= 61000) return;
  const float *xp, *cp; int local;
  if (n < 4000)      { xp=xSB; cp=cSB; local=n; }
  else if (n < 34000){ xp=xPQ; cp=cPQ; local=n-4000; }
  else if (n < 49000){ xp=xPV; cp=cPV; local=n-34000; }
  else               { xp=xNB; cp=cNB; local=n-49000; }
  float4 a = ((const float4*)xp)[local];
  float4 b = ((const float4*)cp)[local];
  ((float4*)xall)[n*2+0] = a;
  ((float4*)xall)[n*2+1] = b;
}

__device__ __forceinline__ float dot128(const float* __restrict__ a, const float* __restrict__ b){
  const float4* a4 = (const float4*)a; const float4* b4 = (const float4*)b;
  float s = 0.f;
  #pragma unroll
  for (int h=0; h<32; h++){
    float4 A=a4[h], B=b4[h];
    s = fmaf(A.x,B.x,s); s = fmaf(A.y,B.y,s); s = fmaf(A.z,B.z,s); s = fmaf(A.w,B.w,s);
  }
  return s;
}
__device__ __forceinline__ void halfsum(const float* __restrict__ a, float& s0, float& s1){
  const float4* a4 = (const float4*)a;
  float x0=0.f, x1=0.f;
  #pragma unroll
  for (int h=0; h<16; h++){ float4 A=a4[h]; x0 += A.x+A.y+A.z+A.w; }
  #pragma unroll
  for (int h=16; h<32; h++){ float4 A=a4[h]; x1 += A.x+A.y+A.z+A.w; }
  s0=x0; s1=x1;
}

// ---- derive per-conv small params (160 floats per conv) ----
__global__ __launch_bounds__(128) void k_params(
    const float* __restrict__ Wq, const float* __restrict__ bq,
    const float* __restrict__ Wk, const float* __restrict__ bk,
    const float* __restrict__ Wv, const float* __restrict__ bv,
    const float* __restrict__ We, const float* __restrict__ be,
    const float* __restrict__ Ws, const float* __restrict__ bs,
    float* __restrict__ par){
  const int c = blockIdx.x, tid = threadIdx.x;
  const float* wq = Wq + (size_t)c*1024;
  const float* wk = Wk + (size_t)c*1024;
  const float* wv = Wv + (size_t)c*1024;
  const float* ws = Ws + (size_t)c*1024;
  const float* we = We + (size_t)c*256;
  const float* vbq = bq + (size_t)c*128;
  const float* vbk = bk + (size_t)c*128;
  const float* vbv = bv + (size_t)c*128;
  const float* vbe = be + (size_t)c*128;
  const float* vbs = bs + (size_t)c*128;
  float* P = par + (size_t)c*160;
  if (tid < 64){
    int fd = tid>>3, fs = tid&7;
    P[tid] = dot128(wq + fd*128, wk + fs*128);
    return;
  }
  const int job = tid - 64, grp = job>>3, f = job&7;
  if (grp==0) P[64+f] = dot128(wq + f*128, vbk);
  else if (grp==1) P[72+f] = dot128(wk + f*128, vbq);
  else if (grp==2) P[80+f] = dot128(wq + f*128, we);
  else if (grp==3) P[88+f] = dot128(wq + f*128, we+128);
  else if (grp==4) P[96+f] = dot128(wq + f*128, vbe);
  else if (grp==5){ float s0,s1; halfsum(wv + f*128, s0,s1); P[104+f]=s0; P[112+f]=s1; }
  else if (grp==6){ float s0,s1; halfsum(ws + f*128, s0,s1); P[120+f]=s0; P[128+f]=s1; }
  else {
    if (f==0){ P[136] = dot128(vbq, vbk);
               float a,b; halfsum(vbs, a,b); P[148]=a; P[149]=b; }
    else if (f==1) P[137] = dot128(vbq, we);
    else if (f==2) P[138] = dot128(vbq, we+128);
    else if (f==3) P[139] = dot128(vbq, vbe);
    else if (f==4){ float a=0.f,b=0.f; for(int h=0;h<64;h++){a+=we[h]; b+=we[64+h];} P[140]=a; P[141]=b; }
    else if (f==5){ float a=0.f,b=0.f; for(int h=0;h<64;h++){a+=we[128+h]; b+=we[192+h];} P[142]=a; P[143]=b; }
    else if (f==6){ float a,b; halfsum(vbv, a,b); P[144]=a; P[145]=b; }
    else          { float a,b; halfsum(vbe, a,b); P[146]=a; P[147]=b; }
  }
}

#define CHUNK 18750

// ---- stage 1a: per-type histogram of dst>>10 (each edge read once) ----
__global__ __launch_bounds__(1024) void k_count(const int* __restrict__ eidx,
                                                int* __restrict__ gcnt){
  const int t = blockIdx.y;
  __shared__ int cnt[32];
  if (threadIdx.x < 32) cnt[threadIdx.x] = 0;
  __syncthreads();
  const int* __restrict__ dstp = eidx + (size_t)(t*2+1)*NE;
  const int e0 = blockIdx.x*CHUNK, e1 = min(NE, e0+CHUNK);
  for (int e=e0+threadIdx.x; e<e1; e+=1024) atomicAdd(&cnt[dstp[e]>>10], 1);
  __syncthreads();
  if (threadIdx.x < 32 && cnt[threadIdx.x] > 0)
    atomicAdd(&gcnt[c_tprefix[t] + threadIdx.x], cnt[threadIdx.x]);
}

// ---- stage 1b: per-type exclusive scan of bucket counts ----
__global__ void k_scan(const int* __restrict__ gcnt, int* __restrict__ gofs,
                       int* __restrict__ gcur){
  const int t = threadIdx.x;
  if (t >= 15) return;
  const int b0 = c_tprefix[t], b1 = c_tprefix[t+1];
  int run = t*NE;
  for (int b=b0; b<b1; b++){ gofs[b]=run; gcur[b]=run; run += gcnt[b]; }
}

// ---- stage 1c: scatter FULL payload {src<<10|dl, ea_f16x2} into tile buckets.
// All reads sequential (dst/src/ea streamed); writes segmented-coalesced.
// This removes k_tsort's random eid gathers entirely. ----
__global__ __launch_bounds__(1024) void k_scatter(const int* __restrict__ eidx,
    const float* __restrict__ eattr,
    int* __restrict__ gcur, uint2* __restrict__ ebuf){
  const int t = blockIdx.y;
  __shared__ int lcnt[32], lbase[32];
  if (threadIdx.x < 32) lcnt[threadIdx.x] = 0;
  __syncthreads();
  const int* __restrict__ dstp = eidx + (size_t)(t*2+1)*NE;
  const int* __restrict__ srcp = eidx + (size_t)(t*2)*NE;
  const float2* __restrict__ ea2 = (const float2*)eattr + (size_t)t*NE;
  const int e0 = blockIdx.x*CHUNK, e1 = min(NE, e0+CHUNK);
  for (int e=e0+threadIdx.x; e<e1; e+=1024) atomicAdd(&lcnt[dstp[e]>>10], 1);
  __syncthreads();
  if (threadIdx.x < 32){
    int cchk = lcnt[threadIdx.x];
    lbase[threadIdx.x] = cchk > 0 ? atomicAdd(&gcur[c_tprefix[t]+threadIdx.x], cchk) : 0;
  }
  __syncthreads();
  if (threadIdx.x < 32) lcnt[threadIdx.x] = 0;
  __syncthreads();
  for (int e=e0+threadIdx.x; e<e1; e+=1024){
    const int d = dstp[e];
    const int tile = d>>10, dl = d&1023;
    const int pos = lbase[tile] + atomicAdd(&lcnt[tile], 1);
    const float2 ea = ea2[e];
    __half2 h2 = __floats2half2_rn(ea.x, ea.y);
    ebuf[pos] = make_uint2(((unsigned)srcp[e]<<10) | (unsigned)dl, *(unsigned*)&h2);
  }
}

// ---- stage 2: per-tile row sort — pure permutation of the 8B payload within
// the bucket (no eidx/eattr access). Pass 1: row histogram + scan -> gs2/glen.
// Pass 2: stream payload, write row-sorted erec {src, ea}. ----
__global__ __launch_bounds__(1024) void k_tsort(
    const uint2* __restrict__ ebuf,
    const int* __restrict__ gofs, const int* __restrict__ gcnt,
    uint2* __restrict__ erec, int* __restrict__ gs2, int* __restrict__ glen){
  const int b = blockIdx.x;
  int t = 0;
  while (b >= c_tprefix[t+1]) ++t;
  const int tile = b - c_tprefix[t];
  const int dt = c_dtype[t];
  const int N = c_N[dt];
  const int nbase = tile << 10;
  const int tileN = min(1024, N - nbase);
  const int tid = threadIdx.x;
  const int lane = tid & 63, wid = tid >> 6;

  __shared__ int cnt[1024];
  __shared__ int wsum[16];

  cnt[tid] = 0;
  __syncthreads();
  const int start = gofs[b], count = gcnt[b];
  for (int k=tid; k<count; k+=1024) atomicAdd(&cnt[ebuf[start+k].x & 1023u], 1);
  __syncthreads();
  const int v = cnt[tid];
  int inc = v;
  #pragma unroll
  for (int off=1; off<64; off<<=1){ int u = __shfl_up(inc, off); if (lane>=off) inc += u; }
  if (lane==63) wsum[wid] = inc;
  __syncthreads();
  if (tid==0){ int r=0; for (int k=0;k<16;k++){ int x=wsum[k]; wsum[k]=r; r+=x; } }
  __syncthreads();
  const int pref = wsum[wid] + inc - v;  // exclusive prefix within bucket
  if (tid < tileN){
    gs2 [c_toff2[t] + nbase + tid] = start + pref;
    glen[c_toff2[t] + nbase + tid] = v;
  }
  cnt[tid] = pref;
  __syncthreads();

  for (int k=tid; k<count; k+=1024){
    const uint2 u2 = ebuf[start+k];
    const int dl = u2.x & 1023u;
    const int pos = start + atomicAdd(&cnt[dl], 1);
    erec[pos] = make_uint2(u2.x >> 10, u2.y);
  }
}

// ---- gather: per (type,node) walk sorted run ONCE, both layers' convs in
// registers. Zero LDS/atomics in the loop. Fuses softmax, skip, minmax.
__global__ __launch_bounds__(256) void k_gather(
    const int* __restrict__ gs2, const int* __restrict__ glen,
    const uint2* __restrict__ erec,
    const float* __restrict__ xall, const float* __restrict__ par,
    const float* __restrict__ Wl, const float* __restrict__ bl,
    float* __restrict__ g, unsigned* __restrict__ mm){
  const int t = blockIdx.y;
  const int dt = c_dtype[t], st = c_stype[t];
  const int N = c_N[dt];
  if (blockIdx.x*256 >= N) return;
  __shared__ float sA[160], sB[160];
  __shared__ float wlb[192];
  __shared__ float smin[4], smax[4];
  const int tid = threadIdx.x;
  if (tid < 160){ sA[tid] = par[(size_t)t*160 + tid]; sB[tid] = par[(size_t)(15+t)*160 + tid]; }
  if (tid < 192) wlb[tid] = (tid<128)? Wl[tid] : bl[tid-128];
  __syncthreads();
  const int n = blockIdx.x*256 + tid;
  const bool valid = n < N;
  float lmin = 3.4e38f, lmax = -3.4e38f;
  if (valid){
    const float4* xdp = (const float4*)(xall + (size_t)(c_xoff[dt]+n)*8);
    float4 b0v = xdp[0], b1v = xdp[1];
    float xd[8] = {b0v.x,b0v.y,b0v.z,b0v.w,b1v.x,b1v.y,b1v.z,b1v.w};
    float r2a[8], r2b[8];
    #pragma unroll
    for (int fs=0; fs<8; fs++){
      float a = sA[72+fs], bb = sB[72+fs];
      #pragma unroll
      for (int fd=0; fd<8; fd++){ a = fmaf(xd[fd], sA[fd*8+fs], a); bb = fmaf(xd[fd], sB[fd*8+fs], bb); }
      r2a[fs]=a; r2b[fs]=bb;
    }
    float t0a=sA[137], t1a=sA[138], tba=sA[139], u0a=sA[136];
    float t0b=sB[137], t1b=sB[138], tbb=sB[139], u0b=sB[136];
    #pragma unroll
    for (int f=0;f<8;f++){
      t0a = fmaf(xd[f], sA[80+f], t0a);  t0b = fmaf(xd[f], sB[80+f], t0b);
      t1a = fmaf(xd[f], sA[88+f], t1a);  t1b = fmaf(xd[f], sB[88+f], t1b);
      tba = fmaf(xd[f], sA[96+f], tba);  tbb = fmaf(xd[f], sB[96+f], tbb);
      u0a = fmaf(xd[f], sA[64+f], u0a);  u0b = fmaf(xd[f], sB[64+f], u0b);
    }
    const float accda = u0a + tba, accdb = u0b + tbb;
    const int o = c_toff2[t];
    const int js = gs2[o+n], je = js + glen[o+n];
    float denA=0.f, n0A=0.f, n1A=0.f;
    float denB=0.f, n0B=0.f, n1B=0.f;
    for (int j=js; j<je; j++){
      const uint2 rec = erec[j];
      const int src = (int)rec.x;
      const __half2 h2 = *(const __half2*)&rec.y;
      const float eax = __low2float(h2), eay = __high2float(h2);
      const float4* xsp = (const float4*)(xall + (size_t)(c_xoff[st]+src)*8);
      float4 a0v = xsp[0], a1v = xsp[1];
      float xs[8] = {a0v.x,a0v.y,a0v.z,a0v.w,a1v.x,a1v.y,a1v.z,a1v.w};
      float accA = accda, accB = accdb;
      float v0A = fmaf(eax, sA[140], fmaf(eay, sA[142], sA[144]+sA[146]));
      float v1A = fmaf(eax, sA[141], fmaf(eay, sA[143], sA[145]+sA[147]));
      float v0B = fmaf(eax, sB[140], fmaf(eay, sB[142], sB[144]+sB[146]));
      float v1B = fmaf(eax, sB[141], fmaf(eay, sB[143], sB[145]+sB[147]));
      #pragma unroll
      for (int f=0;f<8;f++){
        accA = fmaf(xs[f], r2a[f], accA);   accB = fmaf(xs[f], r2b[f], accB);
        v0A  = fmaf(xs[f], sA[104+f], v0A); v0B  = fmaf(xs[f], sB[104+f], v0B);
        v1A  = fmaf(xs[f], sA[112+f], v1A); v1B  = fmaf(xs[f], sB[112+f], v1B);
      }
      accA = fmaf(eax, t0a, fmaf(eay, t1a, accA));
      accB = fmaf(eax, t0b, fmaf(eay, t1b, accB));
      const float peA = __expf(accA * 0.08838834764831845f);
      const float peB = __expf(accB * 0.08838834764831845f);
      denA += peA; n0A = fmaf(peA, v0A, n0A); n1A = fmaf(peA, v1A, n1A);
      denB += peB; n0B = fmaf(peB, v0B, n0B); n1B = fmaf(peB, v1B, n1B);
    }
    const float invA = 1.0f/(denA + 1e-16f);
    const float invB = 1.0f/(denB + 1e-16f);
    float s0a = fmaf(n0A, invA, sA[148]), s1a = fmaf(n1A, invA, sA[149]);
    float s0b = fmaf(n0B, invB, sB[148]), s1b = fmaf(n1B, invB, sB[149]);
    #pragma unroll
    for (int f=0;f<8;f++){
      s0a = fmaf(xd[f], sA[120+f], s0a); s1a = fmaf(xd[f], sA[128+f], s1a);
      s0b = fmaf(xd[f], sB[120+f], s0b); s1b = fmaf(xd[f], sB[128+f], s1b);
    }
    const int baseA = c_aggoff[dt] + (0*c_cnt[dt] + c_slot[t])*N + n;
    const int baseB = c_aggoff[dt] + (1*c_cnt[dt] + c_slot[t])*N + n;
    ((float2*)g)[baseA] = make_float2(s0a, s1a);
    ((float2*)g)[baseB] = make_float2(s0b, s1b);
    #pragma unroll
    for (int h=0;h<64;h++){
      float za = fmaf(s0a, wlb[h], fmaf(s1a, wlb[64+h], wlb[128+h]));
      float zb = fmaf(s0b, wlb[h], fmaf(s1b, wlb[64+h], wlb[128+h]));
      lmin = fminf(lmin, fminf(za,zb)); lmax = fmaxf(lmax, fmaxf(za,zb));
    }
  }
  #pragma unroll
  for (int m=32;m>=1;m>>=1){
    lmin = fminf(lmin, __shfl_xor(lmin,m));
    lmax = fmaxf(lmax, __shfl_xor(lmax,m));
  }
  const int wv = tid>>6;
  if ((tid&63)==0){ smin[wv]=lmin; smax[wv]=lmax; }
  __syncthreads();
  if (tid==0){
    float mn = fminf(fminf(smin[0],smin[1]), fminf(smin[2],smin[3]));
    float mx = fmaxf(fmaxf(smax[0],smax[1]), fmaxf(smax[2],smax[3]));
    atomicMin(&mm[0], encf(mn));
    atomicMax(&mm[1], encf(mx));
  }
}

// ---- final v7: f16 MFMA matvec. Per wave: 64 rows, M=N=K=64 ->
// 32x mfma_f32_16x16x32_f16. A: row=l&15, k=8*(l>>4)+j. B: col=l&15,
// k=8*(l>>4)+j. D (m89-verified): col=l&15, row=4*(l>>4)+reg.
// Epilogue: elu + 16-lane shfl half-sums, per-row readlane, coalesced stores.
__global__ __launch_bounds__(256, 1) void k_final(
    const float* __restrict__ g, const unsigned* __restrict__ mm,
    const float* __restrict__ Wl, const float* __restrict__ bl,
    const float* __restrict__ Wfc, const float* __restrict__ bfc,
    const float* __restrict__ Wl2, const float* __restrict__ bl2,
    float* __restrict__ out){
  const int gw = blockIdx.x*4 + (threadIdx.x>>6);   // global wave id, 64 rows each
  const int l  = threadIdx.x & 63;
  const int lr = l & 15, lg = l >> 4;
  int nt, wo;
  if (gw < 375)       { nt=0; wo=0; }
  else if (gw < 4125) { nt=1; wo=375; }
  else if (gw < 6000) { nt=2; wo=4125; }
  else                { nt=3; wo=6000; }
  const int R = c_aggrows[nt];
  const int r0 = (gw - wo)*64;   // row base (all nt sizes are x64)
  const float zmin = decf(mm[0]), zmax = decf(mm[1]);
  const float rmin = 0.1f*eluf(zmin);
  const float rmax = 0.9f + 0.1f*eluf(zmax);
  const float s2 = 2.0f/(rmax - rmin + 1e-5f);
  const float cc = fmaf(-rmin, s2, -1.0f);      // nrm = elu(z)*s2 + cc
  // Wl slices for A-build: h = kk*32 + lg*8 + j  (contiguous 8 per lane-group)
  float wl0v[2][8], wl1v[2][8], blv[2][8];
  #pragma unroll
  for (int kk=0; kk<2; kk++){
    const int hb = kk*32 + lg*8;
    const float4 a0 = *(const float4*)&Wl[hb],    a1 = *(const float4*)&Wl[hb+4];
    const float4 b0 = *(const float4*)&Wl[64+hb], b1 = *(const float4*)&Wl[64+hb+4];
    const float4 c0 = *(const float4*)&bl[hb],    c1 = *(const float4*)&bl[hb+4];
    wl0v[kk][0]=a0.x; wl0v[kk][1]=a0.y; wl0v[kk][2]=a0.z; wl0v[kk][3]=a0.w;
    wl0v[kk][4]=a1.x; wl0v[kk][5]=a1.y; wl0v[kk][6]=a1.z; wl0v[kk][7]=a1.w;
    wl1v[kk][0]=b0.x; wl1v[kk][1]=b0.y; wl1v[kk][2]=b0.z; wl1v[kk][3]=b0.w;
    wl1v[kk][4]=b1.x; wl1v[kk][5]=b1.y; wl1v[kk][6]=b1.z; wl1v[kk][7]=b1.w;
    blv[kk][0]=c0.x;  blv[kk][1]=c0.y;  blv[kk][2]=c0.z;  blv[kk][3]=c0.w;
    blv[kk][4]=c1.x;  blv[kk][5]=c1.y;  blv[kk][6]=c1.z;  blv[kk][7]=c1.w;
  }
  // B fragments (weights): bfrag[kk][ntl] holds W[kk*32+lg*8+j][ntl*16+lr]
  const float* __restrict__ W = Wfc + (size_t)nt*4096;
  f16x8 bfrag[2][4];
  #pragma unroll
  for (int kk=0; kk<2; kk++){
    #pragma unroll
    for (int ntl=0; ntl<4; ntl++){
      #pragma unroll
      for (int j=0; j<8; j++){
        const int h = kk*32 + lg*8 + j;
        bfrag[kk][ntl][j] = (_Float16)W[h*64 + ntl*16 + lr];
      }
    }
  }
  const float bf0 = bfc[nt*64 + lr],      bf1 = bfc[nt*64 + 16 + lr];
  const float bf2 = bfc[nt*64 + 32 + lr], bf3 = bfc[nt*64 + 48 + lr];
  const float2* __restrict__ g2p = (const float2*)g + c_aggoff[nt] + r0;
  float ph0[4][4], ph1[4][4];   // [mt][reg] half-sums (uniform within 16-lane group)
  #pragma unroll
  for (int mt=0; mt<4; mt++){
    // A fragments for 16 rows (rows mt*16 + lr)
    const float2 gv = g2p[mt*16 + lr];
    f16x8 af0, af1;
    #pragma unroll
    for (int j=0; j<8; j++){
      const float z0 = fmaf(gv.x, wl0v[0][j], fmaf(gv.y, wl1v[0][j], blv[0][j]));
      const float z1 = fmaf(gv.x, wl0v[1][j], fmaf(gv.y, wl1v[1][j], blv[1][j]));
      af0[j] = (_Float16)fmaf(elufast(z0), s2, cc);
      af1[j] = (_Float16)fmaf(elufast(z1), s2, cc);
    }
    f32x4 d0 = {0.f,0.f,0.f,0.f}, d1 = {0.f,0.f,0.f,0.f};
    f32x4 d2 = {0.f,0.f,0.f,0.f}, d3 = {0.f,0.f,0.f,0.f};
    d0 = __builtin_amdgcn_mfma_f32_16x16x32_f16(af0, bfrag[0][0], d0, 0,0,0);
    d1 = __builtin_amdgcn_mfma_f32_16x16x32_f16(af0, bfrag[0][1], d1, 0,0,0);
    d2 = __builtin_amdgcn_mfma_f32_16x16x32_f16(af0, bfrag[0][2], d2, 0,0,0);
    d3 = __builtin_amdgcn_mfma_f32_16x16x32_f16(af0, bfrag[0][3], d3, 0,0,0);
    d0 = __builtin_amdgcn_mfma_f32_16x16x32_f16(af1, bfrag[1][0], d0, 0,0,0);
    d1 = __builtin_amdgcn_mfma_f32_16x16x32_f16(af1, bfrag[1][1], d1, 0,0,0);
    d2 = __builtin_amdgcn_mfma_f32_16x16x32_f16(af1, bfrag[1][2], d2, 0,0,0);
    d3 = __builtin_amdgcn_mfma_f32_16x16x32_f16(af1, bfrag[1][3], d3, 0,0,0);
    // epilogue-1: elu + bias, half-sums over o, reduce over the 16 cols (lr)
    #pragma unroll
    for (int reg=0; reg<4; reg++){
      float p0 = elufast(d0[reg] + bf0) + elufast(d1[reg] + bf1);
      float p1 = elufast(d2[reg] + bf2) + elufast(d3[reg] + bf3);
      p0 += __shfl_xor(p0,1); p0 += __shfl_xor(p0,2); p0 += __shfl_xor(p0,4); p0 += __shfl_xor(p0,8);
      p1 += __shfl_xor(p1,1); p1 += __shfl_xor(p1,2); p1 += __shfl_xor(p1,4); p1 += __shfl_xor(p1,8);
      ph0[mt][reg] = p0; ph1[mt][reg] = p1;
    }
  }
  // epilogue-2: per row r, (h0,h1) live at lane ((r&15)>>2)*16, slot [r>>4][r&3]
  const float wl20 = Wl2[l], wl21 = Wl2[64+l], bl2v = bl2[l];
  float* __restrict__ o1 = out + ((size_t)c_outoff[nt] + r0)*64 + l;
  float* __restrict__ o2 = o1 + (size_t)R*64;
  #pragma unroll
  for (int r=0; r<64; r++){
    const int mt = r>>4, rt = r&15;
    const float h0r = RL(ph0[mt][rt&3], (rt>>2)<<4);
    const float h1r = RL(ph1[mt][rt&3], (rt>>2)<<4);
    const float f = elufast(fmaf(h0r, wl20, fmaf(h1r, wl21, bl2v)));
    o1[(size_t)r*64] = f;
    o2[(size_t)r*64] = f;
  }
}

extern "C" void kernel_launch(void* const* d_in, const int* in_sizes, int n_in,
                              void* d_out, int out_size, void* d_ws, size_t ws_size,
                              hipStream_t stream) {
  const float* xSB = (const float*)d_in[0];
  const float* cSB = (const float*)d_in[1];
  const float* xPQ = (const float*)d_in[2];
  const float* cPQ = (const float*)d_in[3];
  const float* xPV = (const float*)d_in[4];
  const float* cPV = (const float*)d_in[5];
  const float* xNB = (const float*)d_in[6];
  const float* cNB = (const float*)d_in[7];
  const int*   eidx = (const int*)d_in[8];
  const float* eattr= (const float*)d_in[9];
  const float* Wq = (const float*)d_in[10];
  const float* bq = (const float*)d_in[11];
  const float* Wk = (const float*)d_in[12];
  const float* bk = (const float*)d_in[13];
  const float* Wv = (const float*)d_in[14];
  const float* bv = (const float*)d_in[15];
  const float* We = (const float*)d_in[16];
  const float* be = (const float*)d_in[17];
  const float* Ws = (const float*)d_in[18];
  const float* bs = (const float*)d_in[19];
  const float* Wl = (const float*)d_in[20];
  const float* bl = (const float*)d_in[21];
  const float* Wfc= (const float*)d_in[22];
  const float* bfc= (const float*)d_in[23];
  const float* Wl2= (const float*)d_in[24];
  const float* bl2= (const float*)d_in[25];

  float* ws    = (float*)d_ws;
  float* xall  = ws + 0;                    // 488000 f
  float* par   = ws + 488000;               // 4800 f
  int* gs2     = (int*)(ws + 492800);       // 240015 i
  int* glen    = (int*)(ws + 732815);       // 240015 i
  int* gcnt    = (int*)(ws + 972830);       // 240 i
  int* gofs    = (int*)(ws + 973070);       // 240 i
  int* gcur    = (int*)(ws + 973310);       // 240 i
  unsigned* mm = (unsigned*)(ws + 973550);  // 2
  uint2* ebuf  = (uint2*)(ws + 973552);     // 2250000 uint2 (payload buckets; 8B-aligned)
  float* g     = ws + 973552;               // 960000 f (aliases ebuf; ebuf dead after k_tsort)
  uint2* erec  = (uint2*)(ws + 5473552);    // 2250000 uint2 (row-sorted payload)
  // end: 9973552 floats ~= 39.9 MB

  hipMemsetAsync(gcnt, 0, 240*sizeof(int), stream);
  hipMemsetAsync(mm,   0xFF, 4, stream);
  hipMemsetAsync(mm+1, 0x00, 4, stream);

  k_build_x<<<(61000+255)/256, 256, 0, stream>>>(xSB,cSB,xPQ,cPQ,xPV,cPV,xNB,cNB, xall);
  k_params<<<30, 128, 0, stream>>>(Wq,bq,Wk,bk,Wv,bv,We,be,Ws,bs, par);
  dim3 gb(8, 15);
  k_count<<<gb, 1024, 0, stream>>>(eidx, gcnt);
  k_scan<<<1, 64, 0, stream>>>(gcnt, gofs, gcur);
  k_scatter<<<gb, 1024, 0, stream>>>(eidx, eattr, gcur, ebuf);
  k_tsort<<<240, 1024, 0, stream>>>(ebuf, gofs, gcnt, erec, gs2, glen);
  dim3 gg((30000+255)/256, 15);
  k_gather<<<gg, 256, 0, stream>>>(gs2, glen, erec, xall, par, Wl, bl, g, mm);
  k_final<<<1875, 256, 0, stream>>>(g, mm, Wl, bl, Wfc, bfc, Wl2, bl2, (float*)d_out);
}